// Round 6
// baseline (21340.193 us; speedup 1.0000x reference)
//
#include <hip/hip_runtime.h>
#include <hip/hip_bf16.h>

// ---------------------------------------------------------------------------
// Acoustic model: embed+prenet -> bi-GRU encoder (scan over B=32, batch T=800)
// -> 2x GRU decoders (scan over T=800, batch B=32) -> linear heads.
// OUTPUT IS FLOAT32. Precision: activations fp32; MFMA bf16 hi/lo split.
// R1: both decoders in ONE dec_k launch -> latency chains overlap.
// R2: WG-flag fence-free handshake (BEST dec: 1878us/chunk) -- RESTORED here.
// R3/R4: packed-H / per-wave-flag variants: no better (sync floor ~9.4us/step).
// R5: 512-thr dec spilled weights (128 VGPR < 192 needed) -> REVERTED.
// R6: persistent t-split encoder. Encoder scans over B with T as batch, so
//     each t-row is an independent 32-step chain: one WG owns 16 t-rows and
//     scans b=0..31 with NO cross-WG sync and NO relaunches. h kept packed
//     (bf16hi|lo u32) in LDS, v_perm unpack to fragments; Whh pre-split once
//     (wsplit_k) to bf16 hi/lo so B-fragments stream L2->MFMA directly; acc
//     init from hoisted egi (gemm01 MODE 2). n-gate recurrent part kept in a
//     separate accumulator (r*(h@Whn+bhn) numerics preserved).
// ---------------------------------------------------------------------------

typedef __bf16 bf16;
typedef bf16 bf16x8 __attribute__((ext_vector_type(8)));
typedef float f32x4 __attribute__((ext_vector_type(4)));
typedef float f32x2 __attribute__((ext_vector_type(2)));
typedef unsigned int u32x4 __attribute__((ext_vector_type(4)));

#define BATCH 32
#define TLEN 800
#define BT (BATCH * TLEN)

__device__ __forceinline__ float bf2f(bf16 v) {
    unsigned short u = __builtin_bit_cast(unsigned short, v);
    unsigned int x = ((unsigned int)u) << 16;
    return __builtin_bit_cast(float, x);
}
__device__ __forceinline__ bf16 f2bf(float f) {
    unsigned int x = __builtin_bit_cast(unsigned int, f);
    unsigned int r = (x + 0x7FFFu + ((x >> 16) & 1u)) >> 16;
    return __builtin_bit_cast(bf16, (unsigned short)r);
}
__device__ __forceinline__ bf16x8 ld8f(const float* p) {
    f32x4 a = *(const f32x4*)p;
    f32x4 b = *(const f32x4*)(p + 4);
    bf16x8 r;
#pragma unroll
    for (int i = 0; i < 4; i++) {
        r[i] = f2bf(a[i]);
        r[i + 4] = f2bf(b[i]);
    }
    return r;
}
// split 8 floats into hi + lo bf16 (hi = rne(v), lo = rne(v - hi))
__device__ __forceinline__ void splitv(f32x4 a, f32x4 b, bf16x8& vh, bf16x8& vl) {
#pragma unroll
    for (int j = 0; j < 4; j++) {
        bf16 h0 = f2bf(a[j]);
        vh[j] = h0;
        vl[j] = f2bf(a[j] - bf2f(h0));
        bf16 h1 = f2bf(b[j]);
        vh[j + 4] = h1;
        vl[j + 4] = f2bf(b[j] - bf2f(h1));
    }
}
__device__ __forceinline__ f32x4 mfma16(bf16x8 a, bf16x8 b, f32x4 c) {
    return __builtin_amdgcn_mfma_f32_16x16x32_bf16(a, b, c, 0, 0, 0);
}
__device__ __forceinline__ float sigm(float x) { return 1.f / (1.f + __expf(-x)); }

// --- LLC-coherent (agent-scope, relaxed) access helpers for cross-WG data ---
__device__ __forceinline__ void cst_f32(float* p, float v) {
    __hip_atomic_store((unsigned int*)p, __builtin_bit_cast(unsigned int, v),
                       __ATOMIC_RELAXED, __HIP_MEMORY_SCOPE_AGENT);
}
__device__ __forceinline__ float cld_f32(const float* p) {
    unsigned int u = __hip_atomic_load((const unsigned int*)p, __ATOMIC_RELAXED,
                                       __HIP_MEMORY_SCOPE_AGENT);
    return __builtin_bit_cast(float, u);
}
__device__ __forceinline__ f32x4 cld_f32x4(const float* p) {
    unsigned long long a = __hip_atomic_load((const unsigned long long*)p,
                                             __ATOMIC_RELAXED,
                                             __HIP_MEMORY_SCOPE_AGENT);
    unsigned long long b = __hip_atomic_load((const unsigned long long*)(p + 2),
                                             __ATOMIC_RELAXED,
                                             __HIP_MEMORY_SCOPE_AGENT);
    f32x2 fa = __builtin_bit_cast(f32x2, a);
    f32x2 fb = __builtin_bit_cast(f32x2, b);
    f32x4 r;
    r[0] = fa[0]; r[1] = fa[1]; r[2] = fb[0]; r[3] = fb[1];
    return r;
}
// unpack 8 packed u32 (bf16hi<<16|bf16lo, ascending k) into hi/lo fragments
__device__ __forceinline__ void unpk8(const unsigned int v[8], bf16x8& ah,
                                      bf16x8& al) {
    u32x4 hw, lw;
#pragma unroll
    for (int i = 0; i < 4; i++) {
        hw[i] = __builtin_amdgcn_perm(v[2 * i + 1], v[2 * i], 0x07060302u);
        lw[i] = __builtin_amdgcn_perm(v[2 * i + 1], v[2 * i], 0x05040100u);
    }
    ah = __builtin_bit_cast(bf16x8, hw);
    al = __builtin_bit_cast(bf16x8, lw);
}

// ---------------------------------------------------------------------------
// Prenet / projection GEMM, 128x128 tile, K=256, split-A, plain-B.
// MODE 0: A row = note_emb[note[...]], +bias, tanh, ldc 256.
// MODE 1: A row = asrc + m*256,        +bias, tanh, ldc 256.
// MODE 2: A row = asrc + m*256,        no bias, no act, ldc 1536 (egi).
// ---------------------------------------------------------------------------
template <int MODE>
__global__ __launch_bounds__(256) void gemm01_k(
    const int* __restrict__ note, const float* __restrict__ asrc,
    const float* __restrict__ W, const float* __restrict__ bias,
    float* __restrict__ out, int t0, int TC) {
    __shared__ bf16 Ah[128][72], Al[128][72], Bs[128][72];  // 55296 B

    const int tid = threadIdx.x;
    const int lane = tid & 63, wv = tid >> 6;
    const int wm = wv & 1, wn = wv >> 1;
    const int l15 = lane & 15, hi = lane >> 4;
    const int bm = blockIdx.x * 128, bn = blockIdx.y * 128;
    const int ch = (tid & 7) * 8, arow = tid >> 3;
    const int LDC = (MODE == 2) ? 1536 : 256;

    f32x4 acc[4][4] = {};
    const float* ap[4];
    if (MODE == 0) {
        int zc = 0;
        for (int i = 0; i < 64; i++) zc += (note[2 * i + 1] == 0) ? 1 : 0;
        const bool n64 = (zc >= 60);
#pragma unroll
        for (int i = 0; i < 4; i++) {
            int m = bm + arow + 32 * i;
            int b = m / TC, tt = m - b * TC;
            int idx = b * TLEN + t0 + tt;
            int id = n64 ? note[2 * idx] : note[idx];
            id = id < 0 ? 0 : (id > 127 ? 127 : id);
            ap[i] = asrc + (size_t)id * 256;
        }
    } else {
#pragma unroll
        for (int i = 0; i < 4; i++) ap[i] = asrc + (size_t)(bm + arow + 32 * i) * 256;
    }

    for (int k0 = 0; k0 < 256; k0 += 64) {
#pragma unroll
        for (int i = 0; i < 4; i++) {
            int row = arow + 32 * i;
            f32x4 va = *(const f32x4*)(ap[i] + k0 + ch);
            f32x4 vb = *(const f32x4*)(ap[i] + k0 + ch + 4);
            bf16x8 vh, vl;
            splitv(va, vb, vh, vl);
            *(bf16x8*)&Ah[row][ch] = vh;
            *(bf16x8*)&Al[row][ch] = vl;
        }
#pragma unroll
        for (int i = 0; i < 4; i++) {
            int row = arow + 32 * i;
            *(bf16x8*)&Bs[row][ch] = ld8f(W + (size_t)(bn + row) * 256 + k0 + ch);
        }
        __syncthreads();
#pragma unroll
        for (int kk = 0; kk < 64; kk += 32) {
            bf16x8 ah[4], al[4], bb[4];
#pragma unroll
            for (int mt = 0; mt < 4; mt++) {
                ah[mt] = *(const bf16x8*)&Ah[wm * 64 + mt * 16 + l15][kk + hi * 8];
                al[mt] = *(const bf16x8*)&Al[wm * 64 + mt * 16 + l15][kk + hi * 8];
            }
#pragma unroll
            for (int nt = 0; nt < 4; nt++)
                bb[nt] = *(const bf16x8*)&Bs[wn * 64 + nt * 16 + l15][kk + hi * 8];
#pragma unroll
            for (int mt = 0; mt < 4; mt++)
#pragma unroll
                for (int nt = 0; nt < 4; nt++) {
                    acc[mt][nt] = mfma16(ah[mt], bb[nt], acc[mt][nt]);
                    acc[mt][nt] = mfma16(al[mt], bb[nt], acc[mt][nt]);
                }
        }
        __syncthreads();
    }

#pragma unroll
    for (int mt = 0; mt < 4; mt++)
#pragma unroll
        for (int nt = 0; nt < 4; nt++) {
            int n = bn + wn * 64 + nt * 16 + l15;
            float bs = (MODE == 2) ? 0.f : bias[n];
#pragma unroll
            for (int r = 0; r < 4; r++) {
                int m = bm + wm * 64 + mt * 16 + hi * 4 + r;
                float v = acc[mt][nt][r] + bs;
                out[(size_t)m * LDC + n] = (MODE == 2) ? v : tanhf(v);
            }
        }
}

// ---------------------------------------------------------------------------
// gi GEMM: 128x64 tile, K=1088, split-A AND split-B, 3-term MFMA.
// Rows t-major m = tt*32 + b; A = [ef_c | eb_c | sig*sigW+sigB] (fp32).
// out fp32 gi, ldc=1536, bias = bih folded.
// ---------------------------------------------------------------------------
__global__ __launch_bounds__(256) void gemm2_k(
    const float* __restrict__ ef, const float* __restrict__ eb,
    const float* __restrict__ sig, const float* __restrict__ sigW,
    const float* __restrict__ sigB, const float* __restrict__ W,
    const float* __restrict__ bias, float* __restrict__ out, int t0, int TC) {
    __shared__ bf16 Ah[128][72], Al[128][72];  // 36864 B
    __shared__ bf16 Bh[64][72], Bl[64][72];    // 18432 B

    const int tid = threadIdx.x;
    const int lane = tid & 63, wv = tid >> 6;
    const int wm = wv & 1, wn = wv >> 1;
    const int l15 = lane & 15, hi = lane >> 4;
    const int bm = blockIdx.x * 128, bn = blockIdx.y * 64;
    const int ch = (tid & 7) * 8, arow = tid >> 3;

    f32x4 acc[4][2] = {};
    int rb[4];
    float sigv[4];
#pragma unroll
    for (int i = 0; i < 4; i++) {
        int m = bm + arow + 32 * i;
        int tt = m >> 5, b = m & 31;
        rb[i] = b * TC + tt;
        sigv[i] = sig[b * TLEN + t0 + tt];
    }

    for (int k0 = 0; k0 < 1088; k0 += 64) {
#pragma unroll
        for (int i = 0; i < 4; i++) {
            int row = arow + 32 * i;
            int k = k0 + ch;
            f32x4 va, vb;
            if (k < 512) {
                va = *(const f32x4*)(ef + (size_t)rb[i] * 512 + k);
                vb = *(const f32x4*)(ef + (size_t)rb[i] * 512 + k + 4);
            } else if (k < 1024) {
                va = *(const f32x4*)(eb + (size_t)rb[i] * 512 + (k - 512));
                vb = *(const f32x4*)(eb + (size_t)rb[i] * 512 + (k - 512) + 4);
            } else {
                f32x4 w0 = *(const f32x4*)(sigW + ch);
                f32x4 w1 = *(const f32x4*)(sigW + ch + 4);
                f32x4 b0 = *(const f32x4*)(sigB + ch);
                f32x4 b1 = *(const f32x4*)(sigB + ch + 4);
                float s = sigv[i];
#pragma unroll
                for (int j = 0; j < 4; j++) {
                    va[j] = s * w0[j] + b0[j];
                    vb[j] = s * w1[j] + b1[j];
                }
            }
            bf16x8 vh, vl;
            splitv(va, vb, vh, vl);
            *(bf16x8*)&Ah[row][ch] = vh;
            *(bf16x8*)&Al[row][ch] = vl;
        }
#pragma unroll
        for (int i = 0; i < 2; i++) {
            int row = arow + 32 * i;  // 0..63
            const float* src = W + (size_t)(bn + row) * 1088 + k0 + ch;
            f32x4 va = *(const f32x4*)src;
            f32x4 vb = *(const f32x4*)(src + 4);
            bf16x8 vh, vl;
            splitv(va, vb, vh, vl);
            *(bf16x8*)&Bh[row][ch] = vh;
            *(bf16x8*)&Bl[row][ch] = vl;
        }
        __syncthreads();
#pragma unroll
        for (int kk = 0; kk < 64; kk += 32) {
            bf16x8 ah[4], al[4], bh[2], bl[2];
#pragma unroll
            for (int mt = 0; mt < 4; mt++) {
                ah[mt] = *(const bf16x8*)&Ah[wm * 64 + mt * 16 + l15][kk + hi * 8];
                al[mt] = *(const bf16x8*)&Al[wm * 64 + mt * 16 + l15][kk + hi * 8];
            }
#pragma unroll
            for (int nt = 0; nt < 2; nt++) {
                bh[nt] = *(const bf16x8*)&Bh[wn * 32 + nt * 16 + l15][kk + hi * 8];
                bl[nt] = *(const bf16x8*)&Bl[wn * 32 + nt * 16 + l15][kk + hi * 8];
            }
#pragma unroll
            for (int mt = 0; mt < 4; mt++)
#pragma unroll
                for (int nt = 0; nt < 2; nt++) {
                    acc[mt][nt] = mfma16(ah[mt], bh[nt], acc[mt][nt]);
                    acc[mt][nt] = mfma16(al[mt], bh[nt], acc[mt][nt]);
                    acc[mt][nt] = mfma16(ah[mt], bl[nt], acc[mt][nt]);
                }
        }
        __syncthreads();
    }

#pragma unroll
    for (int mt = 0; mt < 4; mt++)
#pragma unroll
        for (int nt = 0; nt < 2; nt++) {
            int n = bn + wn * 32 + nt * 16 + l15;
            float bs = bias[n];
#pragma unroll
            for (int r = 0; r < 4; r++) {
                int m = bm + wm * 64 + mt * 16 + hi * 4 + r;
                out[(size_t)m * 1536 + n] = acc[mt][nt][r] + bs;
            }
        }
}

// ---------------------------------------------------------------------------
// Pre-split Whh (both dirs) into bf16 hi/lo global buffers.
// out layout: [dir][hl][1536*512] bf16 (dir-major, hi then lo).
// ---------------------------------------------------------------------------
__global__ __launch_bounds__(256) void wsplit_k(const float* __restrict__ fWhh,
                                                const float* __restrict__ bWhh,
                                                bf16* __restrict__ out) {
    const int idx = (blockIdx.x * 256 + threadIdx.x) * 8;  // grid.x=384: 786432
    const int dir = blockIdx.y;
    const float* src = dir ? bWhh : fWhh;
    bf16* oh = out + (size_t)dir * 2 * 786432;
    bf16* ol = oh + 786432;
    f32x4 a = *(const f32x4*)(src + idx);
    f32x4 b = *(const f32x4*)(src + idx + 4);
    bf16x8 vh, vl;
    splitv(a, b, vh, vl);
    *(bf16x8*)(oh + idx) = vh;
    *(bf16x8*)(ol + idx) = vl;
}

// ---------------------------------------------------------------------------
// Persistent t-split encoder (R6). Grid (ceil(TC/16), 2 dirs), 256 threads.
// Each WG owns 16 t-rows and scans b=0..31 locally: no cross-WG sync ever.
// h carried in regs (fp32 hold) + LDS packed u32 (bf16hi|lo) for A-fragments.
// B-fragments stream from pre-split Whh bf16 (L2-resident). acc_r/acc_z init
// from egi; n-gate input read at epilogue; acc_hn separate (GRU numerics).
// Per-wave cols: j = w*128 + q*16 + l15, q=0..7; rows m = hi*4+r.
// ---------------------------------------------------------------------------
__global__ __launch_bounds__(256, 1) void enc_scan_k(
    int TC, const float* __restrict__ egiF, const float* __restrict__ egiB,
    float* __restrict__ efb, float* __restrict__ ebb,
    const bf16* __restrict__ wsp, const float* __restrict__ fbih,
    const float* __restrict__ fbhh, const float* __restrict__ bbih,
    const float* __restrict__ bbhh) {
    __shared__ unsigned int Apk[16][516];  // 33 KB, pad 4 u32 (bank spread)

    const int dir = blockIdx.y;
    const float* egi = dir ? egiB : egiF;
    float* outb = dir ? ebb : efb;
    const bf16* Wh = wsp + (size_t)dir * 2 * 786432;
    const bf16* Wl = Wh + 786432;
    const float* bih = dir ? bbih : fbih;
    const float* bhh = dir ? bbhh : fbhh;

    const int tid = threadIdx.x;
    const int lane = tid & 63, w = tid >> 6;
    const int l15 = lane & 15, hi = lane >> 4;
    const int ttile = blockIdx.x;

    float bir[8], biz[8], bin[8], bhn[8];
#pragma unroll
    for (int q = 0; q < 8; q++) {
        int j = w * 128 + q * 16 + l15;
        bir[q] = bih[j] + bhh[j];
        biz[q] = bih[512 + j] + bhh[512 + j];
        bin[q] = bih[1024 + j];
        bhn[q] = bhh[1024 + j];
    }
    int trow[4];
#pragma unroll
    for (int r = 0; r < 4; r++) {
        int tr = ttile * 16 + hi * 4 + r;
        trow[r] = tr < TC ? tr : TC - 1;
    }

    f32x4 hold[8];
#pragma unroll
    for (int q = 0; q < 8; q++) hold[q] = f32x4{0.f, 0.f, 0.f, 0.f};

    for (int b = 0; b < 32; b++) {
        const int bsrc = dir ? (31 - b) : b;
        f32x4 acc_r[8], acc_z[8], acc_hn[8];
#pragma unroll
        for (int q = 0; q < 8; q++) {
            int j = w * 128 + q * 16 + l15;
#pragma unroll
            for (int r = 0; r < 4; r++) {
                const float* ep = egi + ((size_t)bsrc * TC + trow[r]) * 1536 + j;
                acc_r[q][r] = ep[0];
                acc_z[q][r] = ep[512];
            }
            acc_hn[q] = f32x4{0.f, 0.f, 0.f, 0.f};
        }
        if (b > 0) {
            for (int kb = 0; kb < 16; kb++) {
                u32x4 qa = *(const u32x4*)&Apk[l15][kb * 32 + hi * 8];
                u32x4 qb = *(const u32x4*)&Apk[l15][kb * 32 + hi * 8 + 4];
                unsigned int v[8] = {qa[0], qa[1], qa[2], qa[3],
                                     qb[0], qb[1], qb[2], qb[3]};
                bf16x8 ah, al;
                unpk8(v, ah, al);
#pragma unroll
                for (int q = 0; q < 8; q++) {
                    int jw = w * 128 + q * 16 + l15;
                    const size_t ko = (size_t)kb * 32 + hi * 8;
                    bf16x8 brh = *(const bf16x8*)(Wh + (size_t)jw * 512 + ko);
                    bf16x8 brl = *(const bf16x8*)(Wl + (size_t)jw * 512 + ko);
                    bf16x8 bzh = *(const bf16x8*)(Wh + (size_t)(512 + jw) * 512 + ko);
                    bf16x8 bzl = *(const bf16x8*)(Wl + (size_t)(512 + jw) * 512 + ko);
                    bf16x8 bnh = *(const bf16x8*)(Wh + (size_t)(1024 + jw) * 512 + ko);
                    bf16x8 bnl = *(const bf16x8*)(Wl + (size_t)(1024 + jw) * 512 + ko);
                    acc_r[q] = mfma16(ah, brh, acc_r[q]);
                    acc_r[q] = mfma16(al, brh, acc_r[q]);
                    acc_r[q] = mfma16(ah, brl, acc_r[q]);
                    acc_z[q] = mfma16(ah, bzh, acc_z[q]);
                    acc_z[q] = mfma16(al, bzh, acc_z[q]);
                    acc_z[q] = mfma16(ah, bzl, acc_z[q]);
                    acc_hn[q] = mfma16(ah, bnh, acc_hn[q]);
                    acc_hn[q] = mfma16(al, bnh, acc_hn[q]);
                    acc_hn[q] = mfma16(ah, bnl, acc_hn[q]);
                }
            }
        }
        __syncthreads();  // all Apk reads done before overwrite
#pragma unroll
        for (int q = 0; q < 8; q++) {
            int j = w * 128 + q * 16 + l15;
#pragma unroll
            for (int r = 0; r < 4; r++) {
                float gin = egi[((size_t)bsrc * TC + trow[r]) * 1536 + 1024 + j];
                float rr = sigm(acc_r[q][r] + bir[q]);
                float zz = sigm(acc_z[q][r] + biz[q]);
                float nn = tanhf(gin + bin[q] + rr * (acc_hn[q][r] + bhn[q]));
                float hnew = (1.f - zz) * nn + zz * hold[q][r];
                hold[q][r] = hnew;
                outb[((size_t)bsrc * TC + trow[r]) * 512 + j] = hnew;
                bf16 hh = f2bf(hnew);
                bf16 hl = f2bf(hnew - bf2f(hh));
                Apk[hi * 4 + r][j] =
                    ((unsigned int)__builtin_bit_cast(unsigned short, hh) << 16) |
                    (unsigned int)__builtin_bit_cast(unsigned short, hl);
            }
        }
        __syncthreads();  // Apk writes visible before next step's reads
    }
}

// ---------------------------------------------------------------------------
// Persistent decoder chunk (R2, best measured). BOTH decoders per launch
// (32 WGs: d=blockIdx.x>>4, g=blockIdx.x&15 = 32-col slice). No LDS in the
// MFMA path; Whh bf16-hi fragments in regs; H fp32; relaxed agent atomics.
// Per-WG flag = last completed absolute step+1; producer: sc H stores +
// syncthreads (vmcnt drain) + tid0 relaxed flag store; consumer: wave0's 16
// lanes poll 16 flags + syncthreads. Own H slice carried in regs (hpreg).
// ---------------------------------------------------------------------------
__global__ __launch_bounds__(256, 1) void dec_k(
    const float* __restrict__ giF, const float* __restrict__ giR,
    const float* __restrict__ WhhF, const float* __restrict__ WhhR,
    const float* __restrict__ bhhF, const float* __restrict__ bhhR,
    float* __restrict__ HcurF, float* __restrict__ HcurR,
    const float* __restrict__ HprevF, const float* __restrict__ HprevR,
    int* __restrict__ flags, int t0, int TC) {
    const int d = blockIdx.x >> 4;
    const int g = blockIdx.x & 15;
    const float* gi = d ? giR : giF;
    const float* Whh = d ? WhhR : WhhF;
    const float* bhh = d ? bhhR : bhhF;
    float* Hcur = d ? HcurR : HcurF;
    const float* Hprev = d ? HprevR : HprevF;
    int* flg = flags + d * 16;

    const int tid = threadIdx.x;
    const int lane = tid & 63, wv = tid >> 6;
    const int mt = wv & 1, jt = wv >> 1;
    const int l15 = lane & 15, hi = lane >> 4;
    const int j_abs = g * 32 + jt * 16 + l15;

    bf16x8 Wf[3][16];
#pragma unroll
    for (int s = 0; s < 3; s++)
#pragma unroll
        for (int kb = 0; kb < 16; kb++)
            Wf[s][kb] = ld8f(Whh + (size_t)(s * 512 + j_abs) * 512 + kb * 32 + hi * 8);

    const float bhr = bhh[j_abs];
    const float bhz = bhh[512 + j_abs];
    const float bhn = bhh[1024 + j_abs];

    float hpreg[4] = {0.f, 0.f, 0.f, 0.f};

    for (int tt = 0; tt < TC; tt++) {
        const int t = t0 + tt;
        float gr[4], gz[4], gn[4];
#pragma unroll
        for (int r = 0; r < 4; r++) {
            int b = mt * 16 + hi * 4 + r;
            const float* gp = gi + ((size_t)tt * BATCH + b) * 1536 + j_abs;
            gr[r] = gp[0];
            gz[r] = gp[512];
            gn[r] = gp[1024];
        }

        f32x4 ar = {}, az = {}, an = {};
        float hp[4] = {0.f, 0.f, 0.f, 0.f};
        if (t > 0) {
            const float* base;
            if (tt > 0) {
                // wait until all 16 producer WGs have published step t-1
                if (wv == 0 && lane < 16) {
                    while (__hip_atomic_load(&flg[lane], __ATOMIC_RELAXED,
                                             __HIP_MEMORY_SCOPE_AGENT) < t)
                        __builtin_amdgcn_s_sleep(1);
                }
                __syncthreads();
                base = Hcur + (size_t)(tt - 1) * BATCH * 512;
            } else {
                base = Hprev + (size_t)(TC - 1) * BATCH * 512;
            }
            const float* ap = base + (size_t)(mt * 16 + l15) * 512 + hi * 8;
#pragma unroll
            for (int half = 0; half < 2; half++) {
                f32x4 raw[8][2];
#pragma unroll
                for (int q = 0; q < 8; q++) {
                    int kb = half * 8 + q;
                    raw[q][0] = cld_f32x4(ap + kb * 32);
                    raw[q][1] = cld_f32x4(ap + kb * 32 + 4);
                }
#pragma unroll
                for (int q = 0; q < 8; q++) {
                    int kb = half * 8 + q;
                    bf16x8 ah, al;
                    splitv(raw[q][0], raw[q][1], ah, al);
                    ar = mfma16(ah, Wf[0][kb], ar);
                    ar = mfma16(al, Wf[0][kb], ar);
                    az = mfma16(ah, Wf[1][kb], az);
                    az = mfma16(al, Wf[1][kb], az);
                    an = mfma16(ah, Wf[2][kb], an);
                    an = mfma16(al, Wf[2][kb], an);
                }
            }
            if (tt > 0) {
#pragma unroll
                for (int r = 0; r < 4; r++) hp[r] = hpreg[r];
            } else {
#pragma unroll
                for (int r = 0; r < 4; r++) {
                    int b = mt * 16 + hi * 4 + r;
                    hp[r] = cld_f32(base + (size_t)b * 512 + j_abs);
                }
            }
        }
#pragma unroll
        for (int r = 0; r < 4; r++) {
            int b = mt * 16 + hi * 4 + r;
            float rr = sigm(gr[r] + ar[r] + bhr);
            float zz = sigm(gz[r] + az[r] + bhz);
            float nn = tanhf(gn[r] + rr * (an[r] + bhn));
            float hnew = (1.f - zz) * nn + zz * hp[r];
            cst_f32(&Hcur[((size_t)tt * BATCH + b) * 512 + j_abs], hnew);
            hpreg[r] = hnew;
        }
        // syncthreads emits s_waitcnt vmcnt(0) before s_barrier: all waves'
        // coherent H stores are ACKed at the LLC. tid0 then publishes step t.
        __syncthreads();
        if (tid == 0)
            __hip_atomic_store(&flg[g], t + 1, __ATOMIC_RELAXED,
                               __HIP_MEMORY_SCOPE_AGENT);
    }
}

// ---------------------------------------------------------------------------
// Head: out[b*800 + t0 + tt] = dot(W, H[tt*32+b][:]) + bias  (fp32)
// ---------------------------------------------------------------------------
__global__ __launch_bounds__(256) void post_k(
    const float* __restrict__ H, const float* __restrict__ W,
    const float* __restrict__ bs, float* __restrict__ out, int t0) {
    const int wv = threadIdx.x >> 6, lane = threadIdx.x & 63;
    const int row = blockIdx.x * 4 + wv;
    const int tt = row >> 5, b = row & 31;
    const float bias = bs[0];
    const float* hp = H + (size_t)row * 512 + lane * 8;
    f32x4 h0 = *(const f32x4*)hp;
    f32x4 h1 = *(const f32x4*)(hp + 4);
    f32x4 w0 = *(const f32x4*)(W + lane * 8);
    f32x4 w1 = *(const f32x4*)(W + lane * 8 + 4);
    float s = 0.f;
#pragma unroll
    for (int i = 0; i < 4; i++) s += h0[i] * w0[i] + h1[i] * w1[i];
#pragma unroll
    for (int off = 32; off > 0; off >>= 1) s += __shfl_down(s, off);
    if (lane == 0) out[b * TLEN + t0 + tt] = s + bias;
}

__global__ void zero_k(int* __restrict__ flags) {
    int i = blockIdx.x * 256 + threadIdx.x;
    if (i < 2 * TLEN)
        __hip_atomic_store(&flags[i], 0, __ATOMIC_RELAXED,
                           __HIP_MEMORY_SCOPE_AGENT);
}

// ---------------------------------------------------------------------------
extern "C" void kernel_launch(void* const* d_in, const int* in_sizes, int n_in,
                              void* d_out, int out_size, void* d_ws, size_t ws_size,
                              hipStream_t stream) {
    const int* note = (const int*)d_in[0];
    const float* f0_prev = (const float*)d_in[1];
    const float* rmse_prev = (const float*)d_in[2];
    const float* note_emb = (const float*)d_in[3];
    const float* f0_W = (const float*)d_in[4];
    const float* f0_b = (const float*)d_in[5];
    const float* rmse_W = (const float*)d_in[6];
    const float* rmse_b = (const float*)d_in[7];
    const float* pre1_W = (const float*)d_in[8];
    const float* pre1_b = (const float*)d_in[9];
    const float* pre2_W = (const float*)d_in[10];
    const float* pre2_b = (const float*)d_in[11];
    const float* encf_Wih = (const float*)d_in[12];
    const float* encf_Whh = (const float*)d_in[13];
    const float* encf_bih = (const float*)d_in[14];
    const float* encf_bhh = (const float*)d_in[15];
    const float* encb_Wih = (const float*)d_in[16];
    const float* encb_Whh = (const float*)d_in[17];
    const float* encb_bih = (const float*)d_in[18];
    const float* encb_bhh = (const float*)d_in[19];
    const float* decf_Wih = (const float*)d_in[20];
    const float* decf_Whh = (const float*)d_in[21];
    const float* decf_bih = (const float*)d_in[22];
    const float* decf_bhh = (const float*)d_in[23];
    const float* decr_Wih = (const float*)d_in[24];
    const float* decr_Whh = (const float*)d_in[25];
    const float* decr_bih = (const float*)d_in[26];
    const float* decr_bhh = (const float*)d_in[27];
    const float* postf_W = (const float*)d_in[28];
    const float* postf_b = (const float*)d_in[29];
    const float* postr_W = (const float*)d_in[30];
    const float* postr_b = (const float*)d_in[31];
    float* out = (float*)d_out;  // reference output dtype is float32

    // --- choose chunk size TC from ws_size (multiple of 4, divides 800) ---
    // per-TC: ef/eb 2*65536 + gi/egi 2*196608 + H rings 2*slots*65536; plus
    // constant 6.3 MB for pre-split Whh.
    const int tcs[9] = {800, 400, 200, 100, 80, 40, 20, 8, 4};
    int TC = 4;
    for (int i = 0; i < 9; i++) {
        int tc = tcs[i];
        int slots = (tc == TLEN) ? 1 : 2;
        size_t need = (size_t)(2 * 65536 + 2 * 196608 + 2 * slots * 65536) * tc +
                      6291456 + 131072;
        if (ws_size >= need) { TC = tc; break; }
    }
    const int NC = TLEN / TC;
    const int slots = (NC == 1) ? 1 : 2;

    char* ws = (char*)d_ws;
    size_t off = 0;
    auto carve = [&](size_t bytes) {
        void* p = ws + off;
        off += (bytes + 255) & ~(size_t)255;
        return p;
    };
    const size_t slotB = (size_t)65536 * TC;  // TC*32*512*4 bytes (fp32)
    float* ef_c = (float*)carve(slotB);
    float* eb_c = (float*)carve(slotB);
    float* giF_c = (float*)carve((size_t)196608 * TC);
    float* giR_c = (float*)carve((size_t)196608 * TC);
    float* ringF = (float*)carve(slotB * slots);
    float* ringR = (float*)carve(slotB * slots);
    bf16* wsp = (bf16*)carve(6291456);  // [2 dirs][hi,lo][1536*512] bf16
    int* flags = (int*)carve(2 * TLEN * 4);

    // egi aliases giF/giR (both dead until gemm2 runs, after enc consumed egi)
    float* egiF = giF_c;
    float* egiB = giR_c;

    zero_k<<<dim3(7), 256, 0, stream>>>(flags);
    wsplit_k<<<dim3(384, 2), 256, 0, stream>>>(encf_Whh, encb_Whh, wsp);

    const size_t slotE = (size_t)TC * BATCH * 512;  // floats per ring slot

    for (int c = 0; c < NC; c++) {
        const int t0 = c * TC;
        const int mg = TC * 32 / 128;  // 4 | TC -> exact
        const int cs = c & (slots - 1), ps = (c - 1) & (slots - 1);

        // prenet temporaries live in the CURRENT H-ring slots (dead until
        // dec_k rewrites them later this chunk; prev slots untouched).
        float* t1_c = ringF + (size_t)cs * slotE;    // 32*TC x 256 fp32
        float* hpre_c = ringR + (size_t)cs * slotE;  // 32*TC x 256 fp32

        gemm01_k<0><<<dim3(mg, 2), 256, 0, stream>>>(note, note_emb, pre1_W, pre1_b,
                                                     t1_c, t0, TC);
        gemm01_k<1><<<dim3(mg, 2), 256, 0, stream>>>(nullptr, t1_c, pre2_W, pre2_b,
                                                     hpre_c, t0, TC);
        // egi = hpre @ Wih^T per dir (no bias/act; ldc 1536)
        gemm01_k<2><<<dim3(mg, 12), 256, 0, stream>>>(nullptr, hpre_c, encf_Wih,
                                                      nullptr, egiF, t0, TC);
        gemm01_k<2><<<dim3(mg, 12), 256, 0, stream>>>(nullptr, hpre_c, encb_Wih,
                                                      nullptr, egiB, t0, TC);

        // persistent t-split encoder: one launch per chunk, no cross-WG sync
        const int ttiles = (TC + 15) / 16;
        enc_scan_k<<<dim3(ttiles, 2), 256, 0, stream>>>(
            TC, egiF, egiB, ef_c, eb_c, wsp, encf_bih, encf_bhh, encb_bih,
            encb_bhh);

        // gi for both decoders (clobbers egiF/egiB -- encoder is done)
        gemm2_k<<<dim3(mg, 24), 256, 0, stream>>>(ef_c, eb_c, f0_prev, f0_W, f0_b,
                                                  decf_Wih, decf_bih, giF_c, t0, TC);
        gemm2_k<<<dim3(mg, 24), 256, 0, stream>>>(ef_c, eb_c, rmse_prev, rmse_W,
                                                  rmse_b, decr_Wih, decr_bih, giR_c,
                                                  t0, TC);

        float* HcurF = ringF + (size_t)cs * slotE;
        const float* HprevF = ringF + (size_t)ps * slotE;
        float* HcurR = ringR + (size_t)cs * slotE;
        const float* HprevR = ringR + (size_t)ps * slotE;

        // BOTH decoders in one launch: 32 WGs, d = blockIdx.x>>4
        dec_k<<<dim3(32), 256, 0, stream>>>(giF_c, giR_c, decf_Whh, decr_Whh,
                                            decf_bhh, decr_bhh, HcurF, HcurR,
                                            HprevF, HprevR, flags, t0, TC);

        post_k<<<dim3(TC * 32 / 4), 256, 0, stream>>>(HcurF, postf_W, postf_b,
                                                      out, t0);
        post_k<<<dim3(TC * 32 / 4), 256, 0, stream>>>(HcurR, postr_W, postr_b,
                                                      out + BT, t0);
    }
    (void)in_sizes; (void)n_in; (void)out_size; (void)ws_size;
}

// Round 7
// 12882.344 us; speedup vs baseline: 1.6565x; 1.6565x over previous
//
#include <hip/hip_runtime.h>
#include <hip/hip_bf16.h>

// ---------------------------------------------------------------------------
// Acoustic model: embed+prenet -> bi-GRU encoder (scan over B=32, batch T=800)
// -> 2x GRU decoders (scan over T=800, batch B=32) -> linear heads.
// OUTPUT IS FLOAT32. Precision: activations fp32; MFMA bf16 hi/lo split.
// R1: both decoders in ONE dec_k launch -> latency chains overlap.
// R2: WG-flag fence-free handshake (BEST: 11995us total) -- fully restored.
// R3-R6: all regressed (packed-H wbl2 fences; 512-thr VGPR spill; t-split
//        encoder = 8x per-XCD L2 duplication of Whh -> HBM-bound 846MB/disp).
// R7: R2 exact + ONE surgical change: pre-split [Wih|Whh] once into
//     fragment-ordered bf16 hi/lo (wsplit_k, 9.4MB); enc_step loads B
//     fragments DIRECTLY from global (L2-hot, shared by 7 mtile-WGs) --
//     removes all per-step B splitv VALU + B LDS staging (LDS 37KB->9KB).
// ---------------------------------------------------------------------------

typedef __bf16 bf16;
typedef bf16 bf16x8 __attribute__((ext_vector_type(8)));
typedef float f32x4 __attribute__((ext_vector_type(4)));
typedef float f32x2 __attribute__((ext_vector_type(2)));

#define BATCH 32
#define TLEN 800
#define BT (BATCH * TLEN)
#define WROW 768           // concatenated K: 256 (Wih) + 512 (Whh)
#define WELEM 1179648      // 1536 * 768 per dir per (hi|lo)

__device__ __forceinline__ float bf2f(bf16 v) {
    unsigned short u = __builtin_bit_cast(unsigned short, v);
    unsigned int x = ((unsigned int)u) << 16;
    return __builtin_bit_cast(float, x);
}
__device__ __forceinline__ bf16 f2bf(float f) {
    unsigned int x = __builtin_bit_cast(unsigned int, f);
    unsigned int r = (x + 0x7FFFu + ((x >> 16) & 1u)) >> 16;
    return __builtin_bit_cast(bf16, (unsigned short)r);
}
__device__ __forceinline__ bf16x8 ld8f(const float* p) {
    f32x4 a = *(const f32x4*)p;
    f32x4 b = *(const f32x4*)(p + 4);
    bf16x8 r;
#pragma unroll
    for (int i = 0; i < 4; i++) {
        r[i] = f2bf(a[i]);
        r[i + 4] = f2bf(b[i]);
    }
    return r;
}
// split 8 floats into hi + lo bf16 (hi = rne(v), lo = rne(v - hi))
__device__ __forceinline__ void splitv(f32x4 a, f32x4 b, bf16x8& vh, bf16x8& vl) {
#pragma unroll
    for (int j = 0; j < 4; j++) {
        bf16 h0 = f2bf(a[j]);
        vh[j] = h0;
        vl[j] = f2bf(a[j] - bf2f(h0));
        bf16 h1 = f2bf(b[j]);
        vh[j + 4] = h1;
        vl[j + 4] = f2bf(b[j] - bf2f(h1));
    }
}
__device__ __forceinline__ f32x4 mfma16(bf16x8 a, bf16x8 b, f32x4 c) {
    return __builtin_amdgcn_mfma_f32_16x16x32_bf16(a, b, c, 0, 0, 0);
}
__device__ __forceinline__ float sigm(float x) { return 1.f / (1.f + __expf(-x)); }

// --- LLC-coherent (agent-scope, relaxed) access helpers for cross-WG data ---
__device__ __forceinline__ void cst_f32(float* p, float v) {
    __hip_atomic_store((unsigned int*)p, __builtin_bit_cast(unsigned int, v),
                       __ATOMIC_RELAXED, __HIP_MEMORY_SCOPE_AGENT);
}
__device__ __forceinline__ float cld_f32(const float* p) {
    unsigned int u = __hip_atomic_load((const unsigned int*)p, __ATOMIC_RELAXED,
                                       __HIP_MEMORY_SCOPE_AGENT);
    return __builtin_bit_cast(float, u);
}
__device__ __forceinline__ f32x4 cld_f32x4(const float* p) {
    unsigned long long a = __hip_atomic_load((const unsigned long long*)p,
                                             __ATOMIC_RELAXED,
                                             __HIP_MEMORY_SCOPE_AGENT);
    unsigned long long b = __hip_atomic_load((const unsigned long long*)(p + 2),
                                             __ATOMIC_RELAXED,
                                             __HIP_MEMORY_SCOPE_AGENT);
    f32x2 fa = __builtin_bit_cast(f32x2, a);
    f32x2 fb = __builtin_bit_cast(f32x2, b);
    f32x4 r;
    r[0] = fa[0]; r[1] = fa[1]; r[2] = fb[0]; r[3] = fb[1];
    return r;
}

// ---------------------------------------------------------------------------
// Prenet GEMM, 128x128 tile, K=256, split-A (fp32 src), plain-B, tanh epilogue.
// Rows b-major m = b*TC + tt.
// MODE 0: A row = note_emb[note[b*800+t0+tt]]; MODE 1: A row = asrc + m*256.
// out fp32, ldc=256.
// ---------------------------------------------------------------------------
template <int MODE>
__global__ __launch_bounds__(256) void gemm01_k(
    const int* __restrict__ note, const float* __restrict__ asrc,
    const float* __restrict__ W, const float* __restrict__ bias,
    float* __restrict__ out, int t0, int TC) {
    __shared__ bf16 Ah[128][72], Al[128][72], Bs[128][72];  // 55296 B

    const int tid = threadIdx.x;
    const int lane = tid & 63, wv = tid >> 6;
    const int wm = wv & 1, wn = wv >> 1;
    const int l15 = lane & 15, hi = lane >> 4;
    const int bm = blockIdx.x * 128, bn = blockIdx.y * 128;
    const int ch = (tid & 7) * 8, arow = tid >> 3;

    f32x4 acc[4][4] = {};
    const float* ap[4];
    if (MODE == 0) {
        int zc = 0;
        for (int i = 0; i < 64; i++) zc += (note[2 * i + 1] == 0) ? 1 : 0;
        const bool n64 = (zc >= 60);
#pragma unroll
        for (int i = 0; i < 4; i++) {
            int m = bm + arow + 32 * i;
            int b = m / TC, tt = m - b * TC;
            int idx = b * TLEN + t0 + tt;
            int id = n64 ? note[2 * idx] : note[idx];
            id = id < 0 ? 0 : (id > 127 ? 127 : id);
            ap[i] = asrc + (size_t)id * 256;
        }
    } else {
#pragma unroll
        for (int i = 0; i < 4; i++) ap[i] = asrc + (size_t)(bm + arow + 32 * i) * 256;
    }

    for (int k0 = 0; k0 < 256; k0 += 64) {
#pragma unroll
        for (int i = 0; i < 4; i++) {
            int row = arow + 32 * i;
            f32x4 va = *(const f32x4*)(ap[i] + k0 + ch);
            f32x4 vb = *(const f32x4*)(ap[i] + k0 + ch + 4);
            bf16x8 vh, vl;
            splitv(va, vb, vh, vl);
            *(bf16x8*)&Ah[row][ch] = vh;
            *(bf16x8*)&Al[row][ch] = vl;
        }
#pragma unroll
        for (int i = 0; i < 4; i++) {
            int row = arow + 32 * i;
            *(bf16x8*)&Bs[row][ch] = ld8f(W + (size_t)(bn + row) * 256 + k0 + ch);
        }
        __syncthreads();
#pragma unroll
        for (int kk = 0; kk < 64; kk += 32) {
            bf16x8 ah[4], al[4], bb[4];
#pragma unroll
            for (int mt = 0; mt < 4; mt++) {
                ah[mt] = *(const bf16x8*)&Ah[wm * 64 + mt * 16 + l15][kk + hi * 8];
                al[mt] = *(const bf16x8*)&Al[wm * 64 + mt * 16 + l15][kk + hi * 8];
            }
#pragma unroll
            for (int nt = 0; nt < 4; nt++)
                bb[nt] = *(const bf16x8*)&Bs[wn * 64 + nt * 16 + l15][kk + hi * 8];
#pragma unroll
            for (int mt = 0; mt < 4; mt++)
#pragma unroll
                for (int nt = 0; nt < 4; nt++) {
                    acc[mt][nt] = mfma16(ah[mt], bb[nt], acc[mt][nt]);
                    acc[mt][nt] = mfma16(al[mt], bb[nt], acc[mt][nt]);
                }
        }
        __syncthreads();
    }

#pragma unroll
    for (int mt = 0; mt < 4; mt++)
#pragma unroll
        for (int nt = 0; nt < 4; nt++) {
            int n = bn + wn * 64 + nt * 16 + l15;
            float bs = bias[n];
#pragma unroll
            for (int r = 0; r < 4; r++) {
                int m = bm + wm * 64 + mt * 16 + hi * 4 + r;
                out[(size_t)m * 256 + n] = tanhf(acc[mt][nt][r] + bs);
            }
        }
}

// ---------------------------------------------------------------------------
// gi GEMM: 128x64 tile, K=1088, split-A AND split-B, 3-term MFMA.
// Rows t-major m = tt*32 + b; A = [ef_c | eb_c | sig*sigW+sigB] (fp32).
// out fp32 gi, ldc=1536, bias = bih folded.
// ---------------------------------------------------------------------------
__global__ __launch_bounds__(256) void gemm2_k(
    const float* __restrict__ ef, const float* __restrict__ eb,
    const float* __restrict__ sig, const float* __restrict__ sigW,
    const float* __restrict__ sigB, const float* __restrict__ W,
    const float* __restrict__ bias, float* __restrict__ out, int t0, int TC) {
    __shared__ bf16 Ah[128][72], Al[128][72];  // 36864 B
    __shared__ bf16 Bh[64][72], Bl[64][72];    // 18432 B

    const int tid = threadIdx.x;
    const int lane = tid & 63, wv = tid >> 6;
    const int wm = wv & 1, wn = wv >> 1;
    const int l15 = lane & 15, hi = lane >> 4;
    const int bm = blockIdx.x * 128, bn = blockIdx.y * 64;
    const int ch = (tid & 7) * 8, arow = tid >> 3;

    f32x4 acc[4][2] = {};
    int rb[4];
    float sigv[4];
#pragma unroll
    for (int i = 0; i < 4; i++) {
        int m = bm + arow + 32 * i;
        int tt = m >> 5, b = m & 31;
        rb[i] = b * TC + tt;
        sigv[i] = sig[b * TLEN + t0 + tt];
    }

    for (int k0 = 0; k0 < 1088; k0 += 64) {
#pragma unroll
        for (int i = 0; i < 4; i++) {
            int row = arow + 32 * i;
            int k = k0 + ch;
            f32x4 va, vb;
            if (k < 512) {
                va = *(const f32x4*)(ef + (size_t)rb[i] * 512 + k);
                vb = *(const f32x4*)(ef + (size_t)rb[i] * 512 + k + 4);
            } else if (k < 1024) {
                va = *(const f32x4*)(eb + (size_t)rb[i] * 512 + (k - 512));
                vb = *(const f32x4*)(eb + (size_t)rb[i] * 512 + (k - 512) + 4);
            } else {
                f32x4 w0 = *(const f32x4*)(sigW + ch);
                f32x4 w1 = *(const f32x4*)(sigW + ch + 4);
                f32x4 b0 = *(const f32x4*)(sigB + ch);
                f32x4 b1 = *(const f32x4*)(sigB + ch + 4);
                float s = sigv[i];
#pragma unroll
                for (int j = 0; j < 4; j++) {
                    va[j] = s * w0[j] + b0[j];
                    vb[j] = s * w1[j] + b1[j];
                }
            }
            bf16x8 vh, vl;
            splitv(va, vb, vh, vl);
            *(bf16x8*)&Ah[row][ch] = vh;
            *(bf16x8*)&Al[row][ch] = vl;
        }
#pragma unroll
        for (int i = 0; i < 2; i++) {
            int row = arow + 32 * i;  // 0..63
            const float* src = W + (size_t)(bn + row) * 1088 + k0 + ch;
            f32x4 va = *(const f32x4*)src;
            f32x4 vb = *(const f32x4*)(src + 4);
            bf16x8 vh, vl;
            splitv(va, vb, vh, vl);
            *(bf16x8*)&Bh[row][ch] = vh;
            *(bf16x8*)&Bl[row][ch] = vl;
        }
        __syncthreads();
#pragma unroll
        for (int kk = 0; kk < 64; kk += 32) {
            bf16x8 ah[4], al[4], bh[2], bl[2];
#pragma unroll
            for (int mt = 0; mt < 4; mt++) {
                ah[mt] = *(const bf16x8*)&Ah[wm * 64 + mt * 16 + l15][kk + hi * 8];
                al[mt] = *(const bf16x8*)&Al[wm * 64 + mt * 16 + l15][kk + hi * 8];
            }
#pragma unroll
            for (int nt = 0; nt < 2; nt++) {
                bh[nt] = *(const bf16x8*)&Bh[wn * 32 + nt * 16 + l15][kk + hi * 8];
                bl[nt] = *(const bf16x8*)&Bl[wn * 32 + nt * 16 + l15][kk + hi * 8];
            }
#pragma unroll
            for (int mt = 0; mt < 4; mt++)
#pragma unroll
                for (int nt = 0; nt < 2; nt++) {
                    acc[mt][nt] = mfma16(ah[mt], bh[nt], acc[mt][nt]);
                    acc[mt][nt] = mfma16(al[mt], bh[nt], acc[mt][nt]);
                    acc[mt][nt] = mfma16(ah[mt], bl[nt], acc[mt][nt]);
                }
        }
        __syncthreads();
    }

#pragma unroll
    for (int mt = 0; mt < 4; mt++)
#pragma unroll
        for (int nt = 0; nt < 2; nt++) {
            int n = bn + wn * 32 + nt * 16 + l15;
            float bs = bias[n];
#pragma unroll
            for (int r = 0; r < 4; r++) {
                int m = bm + wm * 64 + mt * 16 + hi * 4 + r;
                out[(size_t)m * 1536 + n] = acc[mt][nt][r] + bs;
            }
        }
}

// ---------------------------------------------------------------------------
// Pre-split concatenated encoder weights [Wih | Whh] (both dirs) into
// bf16 hi/lo. Layout: row (s*512 + j), k in 0..767 (k<256 = Wih, else Whh).
// out: [dir][hi,lo][1536*768] bf16.
// ---------------------------------------------------------------------------
__global__ __launch_bounds__(256) void wsplit_k(
    const float* __restrict__ fWih, const float* __restrict__ fWhh,
    const float* __restrict__ bWih, const float* __restrict__ bWhh,
    bf16* __restrict__ out) {
    const int idx = (blockIdx.x * 256 + threadIdx.x) * 8;  // grid.x=576
    const int dir = blockIdx.y;
    const int row = idx / WROW, k = idx - row * WROW;
    const float* src = (k < 256)
                           ? ((dir ? bWih : fWih) + (size_t)row * 256 + k)
                           : ((dir ? bWhh : fWhh) + (size_t)row * 512 + (k - 256));
    bf16* oh = out + (size_t)dir * 2 * WELEM;
    bf16* ol = oh + WELEM;
    f32x4 a = *(const f32x4*)src;
    f32x4 b = *(const f32x4*)(src + 4);
    bf16x8 vh, vl;
    splitv(a, b, vh, vl);
    *(bf16x8*)(oh + idx) = vh;
    *(bf16x8*)(ol + idx) = vl;
}

// ---------------------------------------------------------------------------
// Encoder GRU step (R7): A staged via LDS (unchanged from R2); B fragments
// loaded DIRECTLY from pre-split global bf16 (L2-hot; fragment layout matches
// MFMA operand: row jrow, k = k0+kk+hi*8). No B splitv, no B LDS staging.
// ---------------------------------------------------------------------------
__global__ __launch_bounds__(256) void enc_step_k(
    int step, int TC, const float* __restrict__ hpre, float* __restrict__ efb,
    float* __restrict__ ebb, const bf16* __restrict__ wsp,
    const float* __restrict__ fbih, const float* __restrict__ fbhh,
    const float* __restrict__ bbih, const float* __restrict__ bbhh) {
    __shared__ bf16 As[32][72], Alo[32][72];  // 9216 B only

    const int dir = blockIdx.z;
    const bf16* Wh = wsp + (size_t)dir * 2 * WELEM;
    const bf16* Wl = Wh + WELEM;
    const float* bih = dir ? bbih : fbih;
    const float* bhh = dir ? bbhh : fbhh;
    float* outb = dir ? ebb : efb;
    const int bsrc = dir ? (31 - step) : step;
    const int prevb = dir ? (32 - step) : (step - 1);

    const int tid = threadIdx.x;
    const int lane = tid & 63, wv = tid >> 6;
    const int mt = wv & 1, jt = wv >> 1;
    const int l15 = lane & 15, hi = lane >> 4;
    const int mtile = blockIdx.x, jtile = blockIdx.y;
    const int ch = (tid & 7) * 8, arow = tid >> 3;

    const int jrow = jtile * 32 + jt * 16 + l15;
    const bf16* Whr = Wh + (size_t)jrow * WROW;
    const bf16* Wlr = Wl + (size_t)jrow * WROW;
    const bf16* Whz = Wh + (size_t)(512 + jrow) * WROW;
    const bf16* Wlz = Wl + (size_t)(512 + jrow) * WROW;
    const bf16* Whn = Wh + (size_t)(1024 + jrow) * WROW;
    const bf16* Wln = Wl + (size_t)(1024 + jrow) * WROW;

    f32x4 acc_r = {}, acc_z = {}, acc_in = {}, acc_hn = {};

    const int nblocks = (step == 0) ? 4 : 12;
    for (int kb = 0; kb < nblocks; kb++) {
        int k0 = kb * 64;
        {
            int trow = mtile * 32 + arow;
            int tcl = trow < TC ? trow : TC - 1;
            const float* src = (k0 < 256)
                                   ? (hpre + ((size_t)bsrc * TC + tcl) * 256 + k0 + ch)
                                   : (outb + ((size_t)prevb * TC + tcl) * 512 + (k0 - 256) + ch);
            f32x4 va = *(const f32x4*)src;
            f32x4 vb = *(const f32x4*)(src + 4);
            bf16x8 vh, vl;
            splitv(va, vb, vh, vl);
            *(bf16x8*)&As[arow][ch] = vh;
            *(bf16x8*)&Alo[arow][ch] = vl;
        }
        __syncthreads();
#pragma unroll
        for (int kk = 0; kk < 64; kk += 32) {
            bf16x8 a = *(const bf16x8*)&As[mt * 16 + l15][kk + hi * 8];
            bf16x8 alo = *(const bf16x8*)&Alo[mt * 16 + l15][kk + hi * 8];
            const int ko = k0 + kk + hi * 8;
            bf16x8 brh = *(const bf16x8*)(Whr + ko);
            bf16x8 brl = *(const bf16x8*)(Wlr + ko);
            bf16x8 bzh = *(const bf16x8*)(Whz + ko);
            bf16x8 bzl = *(const bf16x8*)(Wlz + ko);
            bf16x8 bnh = *(const bf16x8*)(Whn + ko);
            bf16x8 bnl = *(const bf16x8*)(Wln + ko);
            acc_r = mfma16(a, brh, acc_r);
            acc_r = mfma16(alo, brh, acc_r);
            acc_r = mfma16(a, brl, acc_r);
            acc_z = mfma16(a, bzh, acc_z);
            acc_z = mfma16(alo, bzh, acc_z);
            acc_z = mfma16(a, bzl, acc_z);
            if (k0 < 256) {
                acc_in = mfma16(a, bnh, acc_in);
                acc_in = mfma16(alo, bnh, acc_in);
                acc_in = mfma16(a, bnl, acc_in);
            } else {
                acc_hn = mfma16(a, bnh, acc_hn);
                acc_hn = mfma16(alo, bnh, acc_hn);
                acc_hn = mfma16(a, bnl, acc_hn);
            }
        }
        __syncthreads();
    }

    int j = jrow;
    float bir = bih[j] + bhh[j];
    float biz = bih[512 + j] + bhh[512 + j];
    float bin = bih[1024 + j];
    float bhn = bhh[1024 + j];
#pragma unroll
    for (int r = 0; r < 4; r++) {
        int trow = mtile * 32 + mt * 16 + hi * 4 + r;
        if (trow < TC) {
            float rr = sigm(acc_r[r] + bir);
            float zz = sigm(acc_z[r] + biz);
            float nn = tanhf(acc_in[r] + bin + rr * (acc_hn[r] + bhn));
            float hp = (step > 0) ? outb[((size_t)prevb * TC + trow) * 512 + j] : 0.f;
            outb[((size_t)bsrc * TC + trow) * 512 + j] = (1.f - zz) * nn + zz * hp;
        }
    }
}

// ---------------------------------------------------------------------------
// Persistent decoder chunk (R2, best measured). BOTH decoders per launch
// (32 WGs: d=blockIdx.x>>4, g=blockIdx.x&15 = 32-col slice). No LDS; Whh
// bf16-hi fragments in regs; H fp32; relaxed agent atomics. Per-WG flag =
// last completed absolute step+1; producer: sc H stores + syncthreads
// (vmcnt drain) + tid0 relaxed flag store; consumer: wave0's 16 lanes poll
// 16 flags + syncthreads. Own H slice carried in regs (hpreg).
// ---------------------------------------------------------------------------
__global__ __launch_bounds__(256, 1) void dec_k(
    const float* __restrict__ giF, const float* __restrict__ giR,
    const float* __restrict__ WhhF, const float* __restrict__ WhhR,
    const float* __restrict__ bhhF, const float* __restrict__ bhhR,
    float* __restrict__ HcurF, float* __restrict__ HcurR,
    const float* __restrict__ HprevF, const float* __restrict__ HprevR,
    int* __restrict__ flags, int t0, int TC) {
    const int d = blockIdx.x >> 4;
    const int g = blockIdx.x & 15;
    const float* gi = d ? giR : giF;
    const float* Whh = d ? WhhR : WhhF;
    const float* bhh = d ? bhhR : bhhF;
    float* Hcur = d ? HcurR : HcurF;
    const float* Hprev = d ? HprevR : HprevF;
    int* flg = flags + d * 16;

    const int tid = threadIdx.x;
    const int lane = tid & 63, wv = tid >> 6;
    const int mt = wv & 1, jt = wv >> 1;
    const int l15 = lane & 15, hi = lane >> 4;
    const int j_abs = g * 32 + jt * 16 + l15;

    bf16x8 Wf[3][16];
#pragma unroll
    for (int s = 0; s < 3; s++)
#pragma unroll
        for (int kb = 0; kb < 16; kb++)
            Wf[s][kb] = ld8f(Whh + (size_t)(s * 512 + j_abs) * 512 + kb * 32 + hi * 8);

    const float bhr = bhh[j_abs];
    const float bhz = bhh[512 + j_abs];
    const float bhn = bhh[1024 + j_abs];

    float hpreg[4] = {0.f, 0.f, 0.f, 0.f};

    for (int tt = 0; tt < TC; tt++) {
        const int t = t0 + tt;
        float gr[4], gz[4], gn[4];
#pragma unroll
        for (int r = 0; r < 4; r++) {
            int b = mt * 16 + hi * 4 + r;
            const float* gp = gi + ((size_t)tt * BATCH + b) * 1536 + j_abs;
            gr[r] = gp[0];
            gz[r] = gp[512];
            gn[r] = gp[1024];
        }

        f32x4 ar = {}, az = {}, an = {};
        float hp[4] = {0.f, 0.f, 0.f, 0.f};
        if (t > 0) {
            const float* base;
            if (tt > 0) {
                // wait until all 16 producer WGs have published step t-1
                if (wv == 0 && lane < 16) {
                    while (__hip_atomic_load(&flg[lane], __ATOMIC_RELAXED,
                                             __HIP_MEMORY_SCOPE_AGENT) < t)
                        __builtin_amdgcn_s_sleep(1);
                }
                __syncthreads();
                base = Hcur + (size_t)(tt - 1) * BATCH * 512;
            } else {
                base = Hprev + (size_t)(TC - 1) * BATCH * 512;
            }
            const float* ap = base + (size_t)(mt * 16 + l15) * 512 + hi * 8;
#pragma unroll
            for (int half = 0; half < 2; half++) {
                f32x4 raw[8][2];
#pragma unroll
                for (int q = 0; q < 8; q++) {
                    int kb = half * 8 + q;
                    raw[q][0] = cld_f32x4(ap + kb * 32);
                    raw[q][1] = cld_f32x4(ap + kb * 32 + 4);
                }
#pragma unroll
                for (int q = 0; q < 8; q++) {
                    int kb = half * 8 + q;
                    bf16x8 ah, al;
                    splitv(raw[q][0], raw[q][1], ah, al);
                    ar = mfma16(ah, Wf[0][kb], ar);
                    ar = mfma16(al, Wf[0][kb], ar);
                    az = mfma16(ah, Wf[1][kb], az);
                    az = mfma16(al, Wf[1][kb], az);
                    an = mfma16(ah, Wf[2][kb], an);
                    an = mfma16(al, Wf[2][kb], an);
                }
            }
            if (tt > 0) {
#pragma unroll
                for (int r = 0; r < 4; r++) hp[r] = hpreg[r];
            } else {
#pragma unroll
                for (int r = 0; r < 4; r++) {
                    int b = mt * 16 + hi * 4 + r;
                    hp[r] = cld_f32(base + (size_t)b * 512 + j_abs);
                }
            }
        }
#pragma unroll
        for (int r = 0; r < 4; r++) {
            int b = mt * 16 + hi * 4 + r;
            float rr = sigm(gr[r] + ar[r] + bhr);
            float zz = sigm(gz[r] + az[r] + bhz);
            float nn = tanhf(gn[r] + rr * (an[r] + bhn));
            float hnew = (1.f - zz) * nn + zz * hp[r];
            cst_f32(&Hcur[((size_t)tt * BATCH + b) * 512 + j_abs], hnew);
            hpreg[r] = hnew;
        }
        // syncthreads emits s_waitcnt vmcnt(0) before s_barrier: all waves'
        // coherent H stores are ACKed at the LLC. tid0 then publishes step t.
        __syncthreads();
        if (tid == 0)
            __hip_atomic_store(&flg[g], t + 1, __ATOMIC_RELAXED,
                               __HIP_MEMORY_SCOPE_AGENT);
    }
}

// ---------------------------------------------------------------------------
// Head: out[b*800 + t0 + tt] = dot(W, H[tt*32+b][:]) + bias  (fp32)
// ---------------------------------------------------------------------------
__global__ __launch_bounds__(256) void post_k(
    const float* __restrict__ H, const float* __restrict__ W,
    const float* __restrict__ bs, float* __restrict__ out, int t0) {
    const int wv = threadIdx.x >> 6, lane = threadIdx.x & 63;
    const int row = blockIdx.x * 4 + wv;
    const int tt = row >> 5, b = row & 31;
    const float bias = bs[0];
    const float* hp = H + (size_t)row * 512 + lane * 8;
    f32x4 h0 = *(const f32x4*)hp;
    f32x4 h1 = *(const f32x4*)(hp + 4);
    f32x4 w0 = *(const f32x4*)(W + lane * 8);
    f32x4 w1 = *(const f32x4*)(W + lane * 8 + 4);
    float s = 0.f;
#pragma unroll
    for (int i = 0; i < 4; i++) s += h0[i] * w0[i] + h1[i] * w1[i];
#pragma unroll
    for (int off = 32; off > 0; off >>= 1) s += __shfl_down(s, off);
    if (lane == 0) out[b * TLEN + t0 + tt] = s + bias;
}

__global__ void zero_k(int* __restrict__ flags) {
    int i = blockIdx.x * 256 + threadIdx.x;
    if (i < 2 * TLEN)
        __hip_atomic_store(&flags[i], 0, __ATOMIC_RELAXED,
                           __HIP_MEMORY_SCOPE_AGENT);
}

// ---------------------------------------------------------------------------
extern "C" void kernel_launch(void* const* d_in, const int* in_sizes, int n_in,
                              void* d_out, int out_size, void* d_ws, size_t ws_size,
                              hipStream_t stream) {
    const int* note = (const int*)d_in[0];
    const float* f0_prev = (const float*)d_in[1];
    const float* rmse_prev = (const float*)d_in[2];
    const float* note_emb = (const float*)d_in[3];
    const float* f0_W = (const float*)d_in[4];
    const float* f0_b = (const float*)d_in[5];
    const float* rmse_W = (const float*)d_in[6];
    const float* rmse_b = (const float*)d_in[7];
    const float* pre1_W = (const float*)d_in[8];
    const float* pre1_b = (const float*)d_in[9];
    const float* pre2_W = (const float*)d_in[10];
    const float* pre2_b = (const float*)d_in[11];
    const float* encf_Wih = (const float*)d_in[12];
    const float* encf_Whh = (const float*)d_in[13];
    const float* encf_bih = (const float*)d_in[14];
    const float* encf_bhh = (const float*)d_in[15];
    const float* encb_Wih = (const float*)d_in[16];
    const float* encb_Whh = (const float*)d_in[17];
    const float* encb_bih = (const float*)d_in[18];
    const float* encb_bhh = (const float*)d_in[19];
    const float* decf_Wih = (const float*)d_in[20];
    const float* decf_Whh = (const float*)d_in[21];
    const float* decf_bih = (const float*)d_in[22];
    const float* decf_bhh = (const float*)d_in[23];
    const float* decr_Wih = (const float*)d_in[24];
    const float* decr_Whh = (const float*)d_in[25];
    const float* decr_bih = (const float*)d_in[26];
    const float* decr_bhh = (const float*)d_in[27];
    const float* postf_W = (const float*)d_in[28];
    const float* postf_b = (const float*)d_in[29];
    const float* postr_W = (const float*)d_in[30];
    const float* postr_b = (const float*)d_in[31];
    float* out = (float*)d_out;  // reference output dtype is float32

    // --- choose chunk size TC from ws_size (multiple of 4, divides 800) ---
    // per-TC bytes: ef/eb 2*65536 + gi 2*196608 + H rings 2*slots*65536,
    // plus constant 9.44 MB pre-split encoder weights.
    const size_t WSPB = (size_t)4 * WELEM * 2;  // 9,437,184 B
    const int tcs[9] = {800, 400, 200, 100, 80, 40, 20, 8, 4};
    int TC = 4;
    for (int i = 0; i < 9; i++) {
        int tc = tcs[i];
        int slots = (tc == TLEN) ? 1 : 2;
        size_t need = (size_t)(2 * 65536 + 2 * 196608 + 2 * slots * 65536) * tc +
                      WSPB + 131072;
        if (ws_size >= need) { TC = tc; break; }
    }
    const int NC = TLEN / TC;
    const int slots = (NC == 1) ? 1 : 2;

    char* ws = (char*)d_ws;
    size_t off = 0;
    auto carve = [&](size_t bytes) {
        void* p = ws + off;
        off += (bytes + 255) & ~(size_t)255;
        return p;
    };
    const size_t slotB = (size_t)65536 * TC;  // TC*32*512*4 bytes (fp32)
    float* ef_c = (float*)carve(slotB);
    float* eb_c = (float*)carve(slotB);
    float* giF_c = (float*)carve((size_t)196608 * TC);
    float* giR_c = (float*)carve((size_t)196608 * TC);
    float* ringF = (float*)carve(slotB * slots);
    float* ringR = (float*)carve(slotB * slots);
    bf16* wsp = (bf16*)carve(WSPB);  // [2 dirs][hi,lo][1536*768] bf16
    int* flags = (int*)carve(2 * TLEN * 4);
    // prenet temporaries alias giF_c (dead once gi is computed): fp32
    float* t1_c = giF_c;                         // 32*TC x 256 fp32
    float* hpre_c = giF_c + (size_t)8192 * TC;   // 32*TC x 256 fp32

    zero_k<<<dim3(7), 256, 0, stream>>>(flags);
    wsplit_k<<<dim3(576, 2), 256, 0, stream>>>(encf_Wih, encf_Whh, encb_Wih,
                                               encb_Whh, wsp);

    const size_t slotE = (size_t)TC * BATCH * 512;

    for (int c = 0; c < NC; c++) {
        const int t0 = c * TC;
        const int mg = TC * 32 / 128;  // 4 | TC -> exact

        gemm01_k<0><<<dim3(mg, 2), 256, 0, stream>>>(note, note_emb, pre1_W, pre1_b,
                                                     t1_c, t0, TC);
        gemm01_k<1><<<dim3(mg, 2), 256, 0, stream>>>(nullptr, t1_c, pre2_W, pre2_b,
                                                     hpre_c, t0, TC);
        const int etiles = (TC + 31) / 32;
        for (int i = 0; i < 32; i++)
            enc_step_k<<<dim3(etiles, 16, 2), 256, 0, stream>>>(
                i, TC, hpre_c, ef_c, eb_c, wsp, encf_bih, encf_bhh, encb_bih,
                encb_bhh);

        // gi for both decoders (gemm2 writes giF after hpre/t1 are dead)
        gemm2_k<<<dim3(mg, 24), 256, 0, stream>>>(ef_c, eb_c, f0_prev, f0_W, f0_b,
                                                  decf_Wih, decf_bih, giF_c, t0, TC);
        gemm2_k<<<dim3(mg, 24), 256, 0, stream>>>(ef_c, eb_c, rmse_prev, rmse_W,
                                                  rmse_b, decr_Wih, decr_bih, giR_c,
                                                  t0, TC);

        float* HcurF = ringF + (size_t)(c & (slots - 1)) * slotE;
        const float* HprevF = ringF + (size_t)((c - 1) & (slots - 1)) * slotE;
        float* HcurR = ringR + (size_t)(c & (slots - 1)) * slotE;
        const float* HprevR = ringR + (size_t)((c - 1) & (slots - 1)) * slotE;

        // BOTH decoders in one launch: 32 WGs, d = blockIdx.x>>4
        dec_k<<<dim3(32), 256, 0, stream>>>(giF_c, giR_c, decf_Whh, decr_Whh,
                                            decf_bhh, decr_bhh, HcurF, HcurR,
                                            HprevF, HprevR, flags, t0, TC);

        post_k<<<dim3(TC * 32 / 4), 256, 0, stream>>>(HcurF, postf_W, postf_b,
                                                      out, t0);
        post_k<<<dim3(TC * 32 / 4), 256, 0, stream>>>(HcurR, postr_W, postr_b,
                                                      out + BT, t0);
    }
    (void)in_sizes; (void)n_in; (void)out_size; (void)ws_size;
}

// Round 8
// 11824.763 us; speedup vs baseline: 1.8047x; 1.0894x over previous
//
#include <hip/hip_runtime.h>
#include <hip/hip_bf16.h>

// ---------------------------------------------------------------------------
// Acoustic model: embed+prenet -> bi-GRU encoder (scan over B=32, batch T=800)
// -> 2x GRU decoders (scan over T=800, batch B=32) -> linear heads.
// OUTPUT IS FLOAT32. Precision: activations fp32; MFMA bf16 hi/lo split.
// R1: both decoders in ONE dec_k launch -> latency chains overlap.
// R2: WG-flag fence-free handshake (best measured: 11995us total).
// R3-R7: protocol/encoder variants all regressed or null; per-step floor
//        pinned at ~9.4us across 4 protocols -> straggler fan-in suspected.
// R8: R2 exact (encoder restored) + dec_k sync-topology remap: batch rows
//     are INDEPENDENT chains, so split each decoder into 2 chains of 16 rows
//     x 8 WGs of 64 cols (was 1 domain of 32 rows x 16 WGs of 32 cols).
//     Work-neutral (same MFMA count, same 192 weight VGPRs -- old layout
//     duplicated weights across the mt batch-halves). Fan-in 16 -> 8, and
//     4 decorrelated sync domains (F0,F1,R0,R1) instead of 2.
// ---------------------------------------------------------------------------

typedef __bf16 bf16;
typedef bf16 bf16x8 __attribute__((ext_vector_type(8)));
typedef float f32x4 __attribute__((ext_vector_type(4)));
typedef float f32x2 __attribute__((ext_vector_type(2)));

#define BATCH 32
#define TLEN 800
#define BT (BATCH * TLEN)

__device__ __forceinline__ float bf2f(bf16 v) {
    unsigned short u = __builtin_bit_cast(unsigned short, v);
    unsigned int x = ((unsigned int)u) << 16;
    return __builtin_bit_cast(float, x);
}
__device__ __forceinline__ bf16 f2bf(float f) {
    unsigned int x = __builtin_bit_cast(unsigned int, f);
    unsigned int r = (x + 0x7FFFu + ((x >> 16) & 1u)) >> 16;
    return __builtin_bit_cast(bf16, (unsigned short)r);
}
__device__ __forceinline__ bf16x8 ld8f(const float* p) {
    f32x4 a = *(const f32x4*)p;
    f32x4 b = *(const f32x4*)(p + 4);
    bf16x8 r;
#pragma unroll
    for (int i = 0; i < 4; i++) {
        r[i] = f2bf(a[i]);
        r[i + 4] = f2bf(b[i]);
    }
    return r;
}
// split 8 floats into hi + lo bf16 (hi = rne(v), lo = rne(v - hi))
__device__ __forceinline__ void splitv(f32x4 a, f32x4 b, bf16x8& vh, bf16x8& vl) {
#pragma unroll
    for (int j = 0; j < 4; j++) {
        bf16 h0 = f2bf(a[j]);
        vh[j] = h0;
        vl[j] = f2bf(a[j] - bf2f(h0));
        bf16 h1 = f2bf(b[j]);
        vh[j + 4] = h1;
        vl[j + 4] = f2bf(b[j] - bf2f(h1));
    }
}
__device__ __forceinline__ f32x4 mfma16(bf16x8 a, bf16x8 b, f32x4 c) {
    return __builtin_amdgcn_mfma_f32_16x16x32_bf16(a, b, c, 0, 0, 0);
}
__device__ __forceinline__ float sigm(float x) { return 1.f / (1.f + __expf(-x)); }

// --- LLC-coherent (agent-scope, relaxed) access helpers for cross-WG data ---
__device__ __forceinline__ void cst_f32(float* p, float v) {
    __hip_atomic_store((unsigned int*)p, __builtin_bit_cast(unsigned int, v),
                       __ATOMIC_RELAXED, __HIP_MEMORY_SCOPE_AGENT);
}
__device__ __forceinline__ float cld_f32(const float* p) {
    unsigned int u = __hip_atomic_load((const unsigned int*)p, __ATOMIC_RELAXED,
                                       __HIP_MEMORY_SCOPE_AGENT);
    return __builtin_bit_cast(float, u);
}
__device__ __forceinline__ f32x4 cld_f32x4(const float* p) {
    unsigned long long a = __hip_atomic_load((const unsigned long long*)p,
                                             __ATOMIC_RELAXED,
                                             __HIP_MEMORY_SCOPE_AGENT);
    unsigned long long b = __hip_atomic_load((const unsigned long long*)(p + 2),
                                             __ATOMIC_RELAXED,
                                             __HIP_MEMORY_SCOPE_AGENT);
    f32x2 fa = __builtin_bit_cast(f32x2, a);
    f32x2 fb = __builtin_bit_cast(f32x2, b);
    f32x4 r;
    r[0] = fa[0]; r[1] = fa[1]; r[2] = fb[0]; r[3] = fb[1];
    return r;
}

// ---------------------------------------------------------------------------
// Prenet GEMM, 128x128 tile, K=256, split-A (fp32 src), plain-B, tanh epilogue.
// Rows b-major m = b*TC + tt.
// MODE 0: A row = note_emb[note[b*800+t0+tt]]; MODE 1: A row = asrc + m*256.
// out fp32, ldc=256.
// ---------------------------------------------------------------------------
template <int MODE>
__global__ __launch_bounds__(256) void gemm01_k(
    const int* __restrict__ note, const float* __restrict__ asrc,
    const float* __restrict__ W, const float* __restrict__ bias,
    float* __restrict__ out, int t0, int TC) {
    __shared__ bf16 Ah[128][72], Al[128][72], Bs[128][72];  // 55296 B

    const int tid = threadIdx.x;
    const int lane = tid & 63, wv = tid >> 6;
    const int wm = wv & 1, wn = wv >> 1;
    const int l15 = lane & 15, hi = lane >> 4;
    const int bm = blockIdx.x * 128, bn = blockIdx.y * 128;
    const int ch = (tid & 7) * 8, arow = tid >> 3;

    f32x4 acc[4][4] = {};
    const float* ap[4];
    if (MODE == 0) {
        int zc = 0;
        for (int i = 0; i < 64; i++) zc += (note[2 * i + 1] == 0) ? 1 : 0;
        const bool n64 = (zc >= 60);
#pragma unroll
        for (int i = 0; i < 4; i++) {
            int m = bm + arow + 32 * i;
            int b = m / TC, tt = m - b * TC;
            int idx = b * TLEN + t0 + tt;
            int id = n64 ? note[2 * idx] : note[idx];
            id = id < 0 ? 0 : (id > 127 ? 127 : id);
            ap[i] = asrc + (size_t)id * 256;
        }
    } else {
#pragma unroll
        for (int i = 0; i < 4; i++) ap[i] = asrc + (size_t)(bm + arow + 32 * i) * 256;
    }

    for (int k0 = 0; k0 < 256; k0 += 64) {
#pragma unroll
        for (int i = 0; i < 4; i++) {
            int row = arow + 32 * i;
            f32x4 va = *(const f32x4*)(ap[i] + k0 + ch);
            f32x4 vb = *(const f32x4*)(ap[i] + k0 + ch + 4);
            bf16x8 vh, vl;
            splitv(va, vb, vh, vl);
            *(bf16x8*)&Ah[row][ch] = vh;
            *(bf16x8*)&Al[row][ch] = vl;
        }
#pragma unroll
        for (int i = 0; i < 4; i++) {
            int row = arow + 32 * i;
            *(bf16x8*)&Bs[row][ch] = ld8f(W + (size_t)(bn + row) * 256 + k0 + ch);
        }
        __syncthreads();
#pragma unroll
        for (int kk = 0; kk < 64; kk += 32) {
            bf16x8 ah[4], al[4], bb[4];
#pragma unroll
            for (int mt = 0; mt < 4; mt++) {
                ah[mt] = *(const bf16x8*)&Ah[wm * 64 + mt * 16 + l15][kk + hi * 8];
                al[mt] = *(const bf16x8*)&Al[wm * 64 + mt * 16 + l15][kk + hi * 8];
            }
#pragma unroll
            for (int nt = 0; nt < 4; nt++)
                bb[nt] = *(const bf16x8*)&Bs[wn * 64 + nt * 16 + l15][kk + hi * 8];
#pragma unroll
            for (int mt = 0; mt < 4; mt++)
#pragma unroll
                for (int nt = 0; nt < 4; nt++) {
                    acc[mt][nt] = mfma16(ah[mt], bb[nt], acc[mt][nt]);
                    acc[mt][nt] = mfma16(al[mt], bb[nt], acc[mt][nt]);
                }
        }
        __syncthreads();
    }

#pragma unroll
    for (int mt = 0; mt < 4; mt++)
#pragma unroll
        for (int nt = 0; nt < 4; nt++) {
            int n = bn + wn * 64 + nt * 16 + l15;
            float bs = bias[n];
#pragma unroll
            for (int r = 0; r < 4; r++) {
                int m = bm + wm * 64 + mt * 16 + hi * 4 + r;
                out[(size_t)m * 256 + n] = tanhf(acc[mt][nt][r] + bs);
            }
        }
}

// ---------------------------------------------------------------------------
// gi GEMM: 128x64 tile, K=1088, split-A AND split-B, 3-term MFMA.
// Rows t-major m = tt*32 + b; A = [ef_c | eb_c | sig*sigW+sigB] (fp32).
// out fp32 gi, ldc=1536, bias = bih folded.
// ---------------------------------------------------------------------------
__global__ __launch_bounds__(256) void gemm2_k(
    const float* __restrict__ ef, const float* __restrict__ eb,
    const float* __restrict__ sig, const float* __restrict__ sigW,
    const float* __restrict__ sigB, const float* __restrict__ W,
    const float* __restrict__ bias, float* __restrict__ out, int t0, int TC) {
    __shared__ bf16 Ah[128][72], Al[128][72];  // 36864 B
    __shared__ bf16 Bh[64][72], Bl[64][72];    // 18432 B

    const int tid = threadIdx.x;
    const int lane = tid & 63, wv = tid >> 6;
    const int wm = wv & 1, wn = wv >> 1;
    const int l15 = lane & 15, hi = lane >> 4;
    const int bm = blockIdx.x * 128, bn = blockIdx.y * 64;
    const int ch = (tid & 7) * 8, arow = tid >> 3;

    f32x4 acc[4][2] = {};
    int rb[4];
    float sigv[4];
#pragma unroll
    for (int i = 0; i < 4; i++) {
        int m = bm + arow + 32 * i;
        int tt = m >> 5, b = m & 31;
        rb[i] = b * TC + tt;
        sigv[i] = sig[b * TLEN + t0 + tt];
    }

    for (int k0 = 0; k0 < 1088; k0 += 64) {
#pragma unroll
        for (int i = 0; i < 4; i++) {
            int row = arow + 32 * i;
            int k = k0 + ch;
            f32x4 va, vb;
            if (k < 512) {
                va = *(const f32x4*)(ef + (size_t)rb[i] * 512 + k);
                vb = *(const f32x4*)(ef + (size_t)rb[i] * 512 + k + 4);
            } else if (k < 1024) {
                va = *(const f32x4*)(eb + (size_t)rb[i] * 512 + (k - 512));
                vb = *(const f32x4*)(eb + (size_t)rb[i] * 512 + (k - 512) + 4);
            } else {
                f32x4 w0 = *(const f32x4*)(sigW + ch);
                f32x4 w1 = *(const f32x4*)(sigW + ch + 4);
                f32x4 b0 = *(const f32x4*)(sigB + ch);
                f32x4 b1 = *(const f32x4*)(sigB + ch + 4);
                float s = sigv[i];
#pragma unroll
                for (int j = 0; j < 4; j++) {
                    va[j] = s * w0[j] + b0[j];
                    vb[j] = s * w1[j] + b1[j];
                }
            }
            bf16x8 vh, vl;
            splitv(va, vb, vh, vl);
            *(bf16x8*)&Ah[row][ch] = vh;
            *(bf16x8*)&Al[row][ch] = vl;
        }
#pragma unroll
        for (int i = 0; i < 2; i++) {
            int row = arow + 32 * i;  // 0..63
            const float* src = W + (size_t)(bn + row) * 1088 + k0 + ch;
            f32x4 va = *(const f32x4*)src;
            f32x4 vb = *(const f32x4*)(src + 4);
            bf16x8 vh, vl;
            splitv(va, vb, vh, vl);
            *(bf16x8*)&Bh[row][ch] = vh;
            *(bf16x8*)&Bl[row][ch] = vl;
        }
        __syncthreads();
#pragma unroll
        for (int kk = 0; kk < 64; kk += 32) {
            bf16x8 ah[4], al[4], bh[2], bl[2];
#pragma unroll
            for (int mt = 0; mt < 4; mt++) {
                ah[mt] = *(const bf16x8*)&Ah[wm * 64 + mt * 16 + l15][kk + hi * 8];
                al[mt] = *(const bf16x8*)&Al[wm * 64 + mt * 16 + l15][kk + hi * 8];
            }
#pragma unroll
            for (int nt = 0; nt < 2; nt++) {
                bh[nt] = *(const bf16x8*)&Bh[wn * 32 + nt * 16 + l15][kk + hi * 8];
                bl[nt] = *(const bf16x8*)&Bl[wn * 32 + nt * 16 + l15][kk + hi * 8];
            }
#pragma unroll
            for (int mt = 0; mt < 4; mt++)
#pragma unroll
                for (int nt = 0; nt < 2; nt++) {
                    acc[mt][nt] = mfma16(ah[mt], bh[nt], acc[mt][nt]);
                    acc[mt][nt] = mfma16(al[mt], bh[nt], acc[mt][nt]);
                    acc[mt][nt] = mfma16(ah[mt], bl[nt], acc[mt][nt]);
                }
        }
        __syncthreads();
    }

#pragma unroll
    for (int mt = 0; mt < 4; mt++)
#pragma unroll
        for (int nt = 0; nt < 2; nt++) {
            int n = bn + wn * 32 + nt * 16 + l15;
            float bs = bias[n];
#pragma unroll
            for (int r = 0; r < 4; r++) {
                int m = bm + wm * 64 + mt * 16 + hi * 4 + r;
                out[(size_t)m * 1536 + n] = acc[mt][nt][r] + bs;
            }
        }
}

// ---------------------------------------------------------------------------
// Encoder GRU step (R2 proven version: LDS staging of A and B, fp32 weights
// split per step). One scan step over B, both dirs via gridDim.z.
// ---------------------------------------------------------------------------
__global__ __launch_bounds__(256) void enc_step_k(
    int step, int TC, const float* __restrict__ hpre, float* __restrict__ efb,
    float* __restrict__ ebb, const float* __restrict__ fWih,
    const float* __restrict__ fWhh, const float* __restrict__ fbih,
    const float* __restrict__ fbhh, const float* __restrict__ bWih,
    const float* __restrict__ bWhh, const float* __restrict__ bbih,
    const float* __restrict__ bbhh) {
    __shared__ bf16 As[32][72], Alo[32][72];   // 9216 B
    __shared__ bf16 Bs[96][72], Blo[96][72];   // 27648 B

    const int dir = blockIdx.z;
    const float* Wih = dir ? bWih : fWih;
    const float* Whh = dir ? bWhh : fWhh;
    const float* bih = dir ? bbih : fbih;
    const float* bhh = dir ? bbhh : fbhh;
    float* outb = dir ? ebb : efb;
    const int bsrc = dir ? (31 - step) : step;
    const int prevb = dir ? (32 - step) : (step - 1);

    const int tid = threadIdx.x;
    const int lane = tid & 63, wv = tid >> 6;
    const int mt = wv & 1, jt = wv >> 1;
    const int l15 = lane & 15, hi = lane >> 4;
    const int mtile = blockIdx.x, jtile = blockIdx.y;
    const int ch = (tid & 7) * 8, arow = tid >> 3;

    f32x4 acc_r = {}, acc_z = {}, acc_in = {}, acc_hn = {};

    const int nblocks = (step == 0) ? 4 : 12;
    for (int kb = 0; kb < nblocks; kb++) {
        int k0 = kb * 64;
        {
            int trow = mtile * 32 + arow;
            int tcl = trow < TC ? trow : TC - 1;
            const float* src = (k0 < 256)
                                   ? (hpre + ((size_t)bsrc * TC + tcl) * 256 + k0 + ch)
                                   : (outb + ((size_t)prevb * TC + tcl) * 512 + (k0 - 256) + ch);
            f32x4 va = *(const f32x4*)src;
            f32x4 vb = *(const f32x4*)(src + 4);
            bf16x8 vh, vl;
            splitv(va, vb, vh, vl);
            *(bf16x8*)&As[arow][ch] = vh;
            *(bf16x8*)&Alo[arow][ch] = vl;
        }
#pragma unroll
        for (int i = 0; i < 3; i++) {
            int row = arow + 32 * i;
            int s = row >> 5, j = row & 31;
            int wr = s * 512 + jtile * 32 + j;
            const float* src = (k0 < 256) ? (Wih + (size_t)wr * 256 + k0 + ch)
                                          : (Whh + (size_t)wr * 512 + (k0 - 256) + ch);
            f32x4 va = *(const f32x4*)src;
            f32x4 vb = *(const f32x4*)(src + 4);
            bf16x8 vh, vl;
            splitv(va, vb, vh, vl);
            *(bf16x8*)&Bs[row][ch] = vh;
            *(bf16x8*)&Blo[row][ch] = vl;
        }
        __syncthreads();
#pragma unroll
        for (int kk = 0; kk < 64; kk += 32) {
            bf16x8 a = *(const bf16x8*)&As[mt * 16 + l15][kk + hi * 8];
            bf16x8 alo = *(const bf16x8*)&Alo[mt * 16 + l15][kk + hi * 8];
            bf16x8 brh = *(const bf16x8*)&Bs[jt * 16 + l15][kk + hi * 8];
            bf16x8 brl = *(const bf16x8*)&Blo[jt * 16 + l15][kk + hi * 8];
            bf16x8 bzh = *(const bf16x8*)&Bs[32 + jt * 16 + l15][kk + hi * 8];
            bf16x8 bzl = *(const bf16x8*)&Blo[32 + jt * 16 + l15][kk + hi * 8];
            bf16x8 bnh = *(const bf16x8*)&Bs[64 + jt * 16 + l15][kk + hi * 8];
            bf16x8 bnl = *(const bf16x8*)&Blo[64 + jt * 16 + l15][kk + hi * 8];
            acc_r = mfma16(a, brh, acc_r);
            acc_r = mfma16(alo, brh, acc_r);
            acc_r = mfma16(a, brl, acc_r);
            acc_z = mfma16(a, bzh, acc_z);
            acc_z = mfma16(alo, bzh, acc_z);
            acc_z = mfma16(a, bzl, acc_z);
            if (k0 < 256) {
                acc_in = mfma16(a, bnh, acc_in);
                acc_in = mfma16(alo, bnh, acc_in);
                acc_in = mfma16(a, bnl, acc_in);
            } else {
                acc_hn = mfma16(a, bnh, acc_hn);
                acc_hn = mfma16(alo, bnh, acc_hn);
                acc_hn = mfma16(a, bnl, acc_hn);
            }
        }
        __syncthreads();
    }

    int j = jtile * 32 + jt * 16 + l15;
    float bir = bih[j] + bhh[j];
    float biz = bih[512 + j] + bhh[512 + j];
    float bin = bih[1024 + j];
    float bhn = bhh[1024 + j];
#pragma unroll
    for (int r = 0; r < 4; r++) {
        int trow = mtile * 32 + mt * 16 + hi * 4 + r;
        if (trow < TC) {
            float rr = sigm(acc_r[r] + bir);
            float zz = sigm(acc_z[r] + biz);
            float nn = tanhf(acc_in[r] + bin + rr * (acc_hn[r] + bhn));
            float hp = (step > 0) ? outb[((size_t)prevb * TC + trow) * 512 + j] : 0.f;
            outb[((size_t)bsrc * TC + trow) * 512 + j] = (1.f - zz) * nn + zz * hp;
        }
    }
}

// ---------------------------------------------------------------------------
// Persistent decoder chunk (R8). BOTH decoders per launch, 32 WGs:
//   d = blockIdx.x>>4 (decoder), c = (blockIdx.x>>3)&1 (16-row batch chain),
//   g = blockIdx.x&7 (64-col group; cols j = g*64 + wv*16 + l15).
// Batch rows are independent chains -> each (d,c) domain syncs only its own
// 8 WGs (fan-in 8, was 16). Weights: Wf[3][16] bf16-hi in regs (192 VGPR,
// no mt duplication now). H fp32, relaxed agent atomics (R2 protocol).
// Producer: sc H stores + syncthreads (vmcnt drain) + tid0 relaxed flag
// store. Consumer: wave0 lanes 0-7 poll own chain's 8 flags + syncthreads.
// Own H slice carried in regs (hpreg).
// ---------------------------------------------------------------------------
__global__ __launch_bounds__(256, 1) void dec_k(
    const float* __restrict__ giF, const float* __restrict__ giR,
    const float* __restrict__ WhhF, const float* __restrict__ WhhR,
    const float* __restrict__ bhhF, const float* __restrict__ bhhR,
    float* __restrict__ HcurF, float* __restrict__ HcurR,
    const float* __restrict__ HprevF, const float* __restrict__ HprevR,
    int* __restrict__ flags, int t0, int TC) {
    const int d = blockIdx.x >> 4;
    const int c = (blockIdx.x >> 3) & 1;
    const int g = blockIdx.x & 7;
    const float* gi = d ? giR : giF;
    const float* Whh = d ? WhhR : WhhF;
    const float* bhh = d ? bhhR : bhhF;
    float* Hcur = d ? HcurR : HcurF;
    const float* Hprev = d ? HprevR : HprevF;
    int* flg = flags + d * 32 + c * 8;  // 8 flags per (decoder, chain)

    const int tid = threadIdx.x;
    const int lane = tid & 63, wv = tid >> 6;
    const int l15 = lane & 15, hi = lane >> 4;
    const int j_abs = g * 64 + wv * 16 + l15;  // 64 cols per WG, 16 per wave
    const int brow = c * 16;                   // chain's base batch row

    bf16x8 Wf[3][16];
#pragma unroll
    for (int s = 0; s < 3; s++)
#pragma unroll
        for (int kb = 0; kb < 16; kb++)
            Wf[s][kb] = ld8f(Whh + (size_t)(s * 512 + j_abs) * 512 + kb * 32 + hi * 8);

    const float bhr = bhh[j_abs];
    const float bhz = bhh[512 + j_abs];
    const float bhn = bhh[1024 + j_abs];

    float hpreg[4] = {0.f, 0.f, 0.f, 0.f};

    for (int tt = 0; tt < TC; tt++) {
        const int t = t0 + tt;
        float gr[4], gz[4], gn[4];
#pragma unroll
        for (int r = 0; r < 4; r++) {
            int b = brow + hi * 4 + r;
            const float* gp = gi + ((size_t)tt * BATCH + b) * 1536 + j_abs;
            gr[r] = gp[0];
            gz[r] = gp[512];
            gn[r] = gp[1024];
        }

        f32x4 ar = {}, az = {}, an = {};
        float hp[4] = {0.f, 0.f, 0.f, 0.f};
        if (t > 0) {
            const float* base;
            if (tt > 0) {
                // wait until this chain's 8 producer WGs published step t-1
                if (wv == 0 && lane < 8) {
                    while (__hip_atomic_load(&flg[lane], __ATOMIC_RELAXED,
                                             __HIP_MEMORY_SCOPE_AGENT) < t)
                        __builtin_amdgcn_s_sleep(1);
                }
                __syncthreads();
                base = Hcur + (size_t)(tt - 1) * BATCH * 512;
            } else {
                base = Hprev + (size_t)(TC - 1) * BATCH * 512;
            }
            // A fragment: row = brow + l15 (chain's 16 rows), k = kb*32+hi*8
            const float* ap = base + (size_t)(brow + l15) * 512 + hi * 8;
#pragma unroll
            for (int half = 0; half < 2; half++) {
                f32x4 raw[8][2];
#pragma unroll
                for (int q = 0; q < 8; q++) {
                    int kb = half * 8 + q;
                    raw[q][0] = cld_f32x4(ap + kb * 32);
                    raw[q][1] = cld_f32x4(ap + kb * 32 + 4);
                }
#pragma unroll
                for (int q = 0; q < 8; q++) {
                    int kb = half * 8 + q;
                    bf16x8 ah, al;
                    splitv(raw[q][0], raw[q][1], ah, al);
                    ar = mfma16(ah, Wf[0][kb], ar);
                    ar = mfma16(al, Wf[0][kb], ar);
                    az = mfma16(ah, Wf[1][kb], az);
                    az = mfma16(al, Wf[1][kb], az);
                    an = mfma16(ah, Wf[2][kb], an);
                    an = mfma16(al, Wf[2][kb], an);
                }
            }
            if (tt > 0) {
#pragma unroll
                for (int r = 0; r < 4; r++) hp[r] = hpreg[r];
            } else {
#pragma unroll
                for (int r = 0; r < 4; r++) {
                    int b = brow + hi * 4 + r;
                    hp[r] = cld_f32(base + (size_t)b * 512 + j_abs);
                }
            }
        }
#pragma unroll
        for (int r = 0; r < 4; r++) {
            int b = brow + hi * 4 + r;
            float rr = sigm(gr[r] + ar[r] + bhr);
            float zz = sigm(gz[r] + az[r] + bhz);
            float nn = tanhf(gn[r] + rr * (an[r] + bhn));
            float hnew = (1.f - zz) * nn + zz * hp[r];
            cst_f32(&Hcur[((size_t)tt * BATCH + b) * 512 + j_abs], hnew);
            hpreg[r] = hnew;
        }
        // syncthreads emits s_waitcnt vmcnt(0) before s_barrier: all waves'
        // coherent H stores are ACKed at the LLC. tid0 then publishes step t.
        __syncthreads();
        if (tid == 0)
            __hip_atomic_store(&flg[g], t + 1, __ATOMIC_RELAXED,
                               __HIP_MEMORY_SCOPE_AGENT);
    }
}

// ---------------------------------------------------------------------------
// Head: out[b*800 + t0 + tt] = dot(W, H[tt*32+b][:]) + bias  (fp32)
// ---------------------------------------------------------------------------
__global__ __launch_bounds__(256) void post_k(
    const float* __restrict__ H, const float* __restrict__ W,
    const float* __restrict__ bs, float* __restrict__ out, int t0) {
    const int wv = threadIdx.x >> 6, lane = threadIdx.x & 63;
    const int row = blockIdx.x * 4 + wv;
    const int tt = row >> 5, b = row & 31;
    const float bias = bs[0];
    const float* hp = H + (size_t)row * 512 + lane * 8;
    f32x4 h0 = *(const f32x4*)hp;
    f32x4 h1 = *(const f32x4*)(hp + 4);
    f32x4 w0 = *(const f32x4*)(W + lane * 8);
    f32x4 w1 = *(const f32x4*)(W + lane * 8 + 4);
    float s = 0.f;
#pragma unroll
    for (int i = 0; i < 4; i++) s += h0[i] * w0[i] + h1[i] * w1[i];
#pragma unroll
    for (int off = 32; off > 0; off >>= 1) s += __shfl_down(s, off);
    if (lane == 0) out[b * TLEN + t0 + tt] = s + bias;
}

__global__ void zero_k(int* __restrict__ flags) {
    int i = blockIdx.x * 256 + threadIdx.x;
    if (i < 2 * TLEN)
        __hip_atomic_store(&flags[i], 0, __ATOMIC_RELAXED,
                           __HIP_MEMORY_SCOPE_AGENT);
}

// ---------------------------------------------------------------------------
extern "C" void kernel_launch(void* const* d_in, const int* in_sizes, int n_in,
                              void* d_out, int out_size, void* d_ws, size_t ws_size,
                              hipStream_t stream) {
    const int* note = (const int*)d_in[0];
    const float* f0_prev = (const float*)d_in[1];
    const float* rmse_prev = (const float*)d_in[2];
    const float* note_emb = (const float*)d_in[3];
    const float* f0_W = (const float*)d_in[4];
    const float* f0_b = (const float*)d_in[5];
    const float* rmse_W = (const float*)d_in[6];
    const float* rmse_b = (const float*)d_in[7];
    const float* pre1_W = (const float*)d_in[8];
    const float* pre1_b = (const float*)d_in[9];
    const float* pre2_W = (const float*)d_in[10];
    const float* pre2_b = (const float*)d_in[11];
    const float* encf_Wih = (const float*)d_in[12];
    const float* encf_Whh = (const float*)d_in[13];
    const float* encf_bih = (const float*)d_in[14];
    const float* encf_bhh = (const float*)d_in[15];
    const float* encb_Wih = (const float*)d_in[16];
    const float* encb_Whh = (const float*)d_in[17];
    const float* encb_bih = (const float*)d_in[18];
    const float* encb_bhh = (const float*)d_in[19];
    const float* decf_Wih = (const float*)d_in[20];
    const float* decf_Whh = (const float*)d_in[21];
    const float* decf_bih = (const float*)d_in[22];
    const float* decf_bhh = (const float*)d_in[23];
    const float* decr_Wih = (const float*)d_in[24];
    const float* decr_Whh = (const float*)d_in[25];
    const float* decr_bih = (const float*)d_in[26];
    const float* decr_bhh = (const float*)d_in[27];
    const float* postf_W = (const float*)d_in[28];
    const float* postf_b = (const float*)d_in[29];
    const float* postr_W = (const float*)d_in[30];
    const float* postr_b = (const float*)d_in[31];
    float* out = (float*)d_out;  // reference output dtype is float32

    // --- choose chunk size TC from ws_size (multiple of 4, divides 800) ---
    // per-TC bytes: ef/eb 2*65536 + gi (BOTH decoders) 2*196608 + H rings
    // 2*slots*65536
    const int tcs[9] = {800, 400, 200, 100, 80, 40, 20, 8, 4};
    int TC = 4;
    for (int i = 0; i < 9; i++) {
        int tc = tcs[i];
        int slots = (tc == TLEN) ? 1 : 2;
        size_t need = (size_t)(2 * 65536 + 2 * 196608 + 2 * slots * 65536) * tc + 65536;
        if (ws_size >= need) { TC = tc; break; }
    }
    const int NC = TLEN / TC;
    const int slots = (NC == 1) ? 1 : 2;

    char* ws = (char*)d_ws;
    size_t off = 0;
    auto carve = [&](size_t bytes) {
        void* p = ws + off;
        off += (bytes + 255) & ~(size_t)255;
        return p;
    };
    const size_t slotB = (size_t)65536 * TC;  // TC*32*512*4 bytes (fp32)
    float* ef_c = (float*)carve(slotB);
    float* eb_c = (float*)carve(slotB);
    float* giF_c = (float*)carve((size_t)196608 * TC);
    float* giR_c = (float*)carve((size_t)196608 * TC);
    float* ringF = (float*)carve(slotB * slots);
    float* ringR = (float*)carve(slotB * slots);
    int* flags = (int*)carve(2 * TLEN * 4);
    // prenet temporaries alias giF_c (dead once gi is computed): fp32
    float* t1_c = giF_c;                         // 32*TC x 256 fp32
    float* hpre_c = giF_c + (size_t)8192 * TC;   // 32*TC x 256 fp32

    zero_k<<<dim3(7), 256, 0, stream>>>(flags);

    const size_t slotE = (size_t)TC * BATCH * 512;

    for (int c = 0; c < NC; c++) {
        const int t0 = c * TC;
        const int mg = TC * 32 / 128;  // 4 | TC -> exact

        gemm01_k<0><<<dim3(mg, 2), 256, 0, stream>>>(note, note_emb, pre1_W, pre1_b,
                                                     t1_c, t0, TC);
        gemm01_k<1><<<dim3(mg, 2), 256, 0, stream>>>(nullptr, t1_c, pre2_W, pre2_b,
                                                     hpre_c, t0, TC);
        const int etiles = (TC + 31) / 32;
        for (int i = 0; i < 32; i++)
            enc_step_k<<<dim3(etiles, 16, 2), 256, 0, stream>>>(
                i, TC, hpre_c, ef_c, eb_c, encf_Wih, encf_Whh, encf_bih, encf_bhh,
                encb_Wih, encb_Whh, encb_bih, encb_bhh);

        // gi for both decoders (gemm2 writes giF after hpre/t1 are dead)
        gemm2_k<<<dim3(mg, 24), 256, 0, stream>>>(ef_c, eb_c, f0_prev, f0_W, f0_b,
                                                  decf_Wih, decf_bih, giF_c, t0, TC);
        gemm2_k<<<dim3(mg, 24), 256, 0, stream>>>(ef_c, eb_c, rmse_prev, rmse_W,
                                                  rmse_b, decr_Wih, decr_bih, giR_c,
                                                  t0, TC);

        float* HcurF = ringF + (size_t)(c & (slots - 1)) * slotE;
        const float* HprevF = ringF + (size_t)((c - 1) & (slots - 1)) * slotE;
        float* HcurR = ringR + (size_t)(c & (slots - 1)) * slotE;
        const float* HprevR = ringR + (size_t)((c - 1) & (slots - 1)) * slotE;

        // BOTH decoders in one launch: 32 WGs, d = bid>>4, chain = (bid>>3)&1
        dec_k<<<dim3(32), 256, 0, stream>>>(giF_c, giR_c, decf_Whh, decr_Whh,
                                            decf_bhh, decr_bhh, HcurF, HcurR,
                                            HprevF, HprevR, flags, t0, TC);

        post_k<<<dim3(TC * 32 / 4), 256, 0, stream>>>(HcurF, postf_W, postf_b,
                                                      out, t0);
        post_k<<<dim3(TC * 32 / 4), 256, 0, stream>>>(HcurR, postr_W, postr_b,
                                                      out + BT, t0);
    }
    (void)in_sizes; (void)n_in; (void)out_size; (void)ws_size;
}

// Round 9
// 11100.639 us; speedup vs baseline: 1.9224x; 1.0652x over previous
//
#include <hip/hip_runtime.h>
#include <hip/hip_bf16.h>

// ---------------------------------------------------------------------------
// Acoustic model: embed+prenet -> bi-GRU encoder (scan over B=32, batch T=800)
// -> 2x GRU decoders (scan over T=800, batch B=32) -> linear heads.
// OUTPUT IS FLOAT32. Precision: activations fp32; MFMA bf16 hi/lo split.
// R1: both decoders in ONE dec_k launch -> latency chains overlap.
// R2: WG-flag fence-free handshake. R8: dec 2x16-row chains, fan-in 8
//     (best: 11825us; dec step period ~9.3us = intrinsic LLC chain floor).
// R9: enc_step kb-loop pipelined. (a) [Wih|Whh] pre-split once to bf16 hi/lo
//     (wsplit_k, bit-identical to in-kernel splitv) -> B staging is a pure
//     16B copy; (b) double-buffered LDS + 1-deep register prefetch + RAW
//     s_barrier (no vmcnt drain; compiler emits counted vmcnt) so kb+1's
//     global-load latency hides under kb's barrier+MFMA. One barrier/iter.
// ---------------------------------------------------------------------------

typedef __bf16 bf16;
typedef bf16 bf16x8 __attribute__((ext_vector_type(8)));
typedef float f32x4 __attribute__((ext_vector_type(4)));
typedef float f32x2 __attribute__((ext_vector_type(2)));

#define BATCH 32
#define TLEN 800
#define BT (BATCH * TLEN)
#define WROW 768           // concatenated K: 256 (Wih) + 512 (Whh)
#define WELEM 1179648      // 1536 * 768 per dir per (hi|lo)

__device__ __forceinline__ float bf2f(bf16 v) {
    unsigned short u = __builtin_bit_cast(unsigned short, v);
    unsigned int x = ((unsigned int)u) << 16;
    return __builtin_bit_cast(float, x);
}
__device__ __forceinline__ bf16 f2bf(float f) {
    unsigned int x = __builtin_bit_cast(unsigned int, f);
    unsigned int r = (x + 0x7FFFu + ((x >> 16) & 1u)) >> 16;
    return __builtin_bit_cast(bf16, (unsigned short)r);
}
__device__ __forceinline__ bf16x8 ld8f(const float* p) {
    f32x4 a = *(const f32x4*)p;
    f32x4 b = *(const f32x4*)(p + 4);
    bf16x8 r;
#pragma unroll
    for (int i = 0; i < 4; i++) {
        r[i] = f2bf(a[i]);
        r[i + 4] = f2bf(b[i]);
    }
    return r;
}
// split 8 floats into hi + lo bf16 (hi = rne(v), lo = rne(v - hi))
__device__ __forceinline__ void splitv(f32x4 a, f32x4 b, bf16x8& vh, bf16x8& vl) {
#pragma unroll
    for (int j = 0; j < 4; j++) {
        bf16 h0 = f2bf(a[j]);
        vh[j] = h0;
        vl[j] = f2bf(a[j] - bf2f(h0));
        bf16 h1 = f2bf(b[j]);
        vh[j + 4] = h1;
        vl[j + 4] = f2bf(b[j] - bf2f(h1));
    }
}
__device__ __forceinline__ f32x4 mfma16(bf16x8 a, bf16x8 b, f32x4 c) {
    return __builtin_amdgcn_mfma_f32_16x16x32_bf16(a, b, c, 0, 0, 0);
}
__device__ __forceinline__ float sigm(float x) { return 1.f / (1.f + __expf(-x)); }

// --- LLC-coherent (agent-scope, relaxed) access helpers for cross-WG data ---
__device__ __forceinline__ void cst_f32(float* p, float v) {
    __hip_atomic_store((unsigned int*)p, __builtin_bit_cast(unsigned int, v),
                       __ATOMIC_RELAXED, __HIP_MEMORY_SCOPE_AGENT);
}
__device__ __forceinline__ float cld_f32(const float* p) {
    unsigned int u = __hip_atomic_load((const unsigned int*)p, __ATOMIC_RELAXED,
                                       __HIP_MEMORY_SCOPE_AGENT);
    return __builtin_bit_cast(float, u);
}
__device__ __forceinline__ f32x4 cld_f32x4(const float* p) {
    unsigned long long a = __hip_atomic_load((const unsigned long long*)p,
                                             __ATOMIC_RELAXED,
                                             __HIP_MEMORY_SCOPE_AGENT);
    unsigned long long b = __hip_atomic_load((const unsigned long long*)(p + 2),
                                             __ATOMIC_RELAXED,
                                             __HIP_MEMORY_SCOPE_AGENT);
    f32x2 fa = __builtin_bit_cast(f32x2, a);
    f32x2 fb = __builtin_bit_cast(f32x2, b);
    f32x4 r;
    r[0] = fa[0]; r[1] = fa[1]; r[2] = fb[0]; r[3] = fb[1];
    return r;
}

// ---------------------------------------------------------------------------
// Prenet GEMM, 128x128 tile, K=256, split-A (fp32 src), plain-B, tanh epilogue.
// Rows b-major m = b*TC + tt.
// MODE 0: A row = note_emb[note[b*800+t0+tt]]; MODE 1: A row = asrc + m*256.
// out fp32, ldc=256.
// ---------------------------------------------------------------------------
template <int MODE>
__global__ __launch_bounds__(256) void gemm01_k(
    const int* __restrict__ note, const float* __restrict__ asrc,
    const float* __restrict__ W, const float* __restrict__ bias,
    float* __restrict__ out, int t0, int TC) {
    __shared__ bf16 Ah[128][72], Al[128][72], Bs[128][72];  // 55296 B

    const int tid = threadIdx.x;
    const int lane = tid & 63, wv = tid >> 6;
    const int wm = wv & 1, wn = wv >> 1;
    const int l15 = lane & 15, hi = lane >> 4;
    const int bm = blockIdx.x * 128, bn = blockIdx.y * 128;
    const int ch = (tid & 7) * 8, arow = tid >> 3;

    f32x4 acc[4][4] = {};
    const float* ap[4];
    if (MODE == 0) {
        int zc = 0;
        for (int i = 0; i < 64; i++) zc += (note[2 * i + 1] == 0) ? 1 : 0;
        const bool n64 = (zc >= 60);
#pragma unroll
        for (int i = 0; i < 4; i++) {
            int m = bm + arow + 32 * i;
            int b = m / TC, tt = m - b * TC;
            int idx = b * TLEN + t0 + tt;
            int id = n64 ? note[2 * idx] : note[idx];
            id = id < 0 ? 0 : (id > 127 ? 127 : id);
            ap[i] = asrc + (size_t)id * 256;
        }
    } else {
#pragma unroll
        for (int i = 0; i < 4; i++) ap[i] = asrc + (size_t)(bm + arow + 32 * i) * 256;
    }

    for (int k0 = 0; k0 < 256; k0 += 64) {
#pragma unroll
        for (int i = 0; i < 4; i++) {
            int row = arow + 32 * i;
            f32x4 va = *(const f32x4*)(ap[i] + k0 + ch);
            f32x4 vb = *(const f32x4*)(ap[i] + k0 + ch + 4);
            bf16x8 vh, vl;
            splitv(va, vb, vh, vl);
            *(bf16x8*)&Ah[row][ch] = vh;
            *(bf16x8*)&Al[row][ch] = vl;
        }
#pragma unroll
        for (int i = 0; i < 4; i++) {
            int row = arow + 32 * i;
            *(bf16x8*)&Bs[row][ch] = ld8f(W + (size_t)(bn + row) * 256 + k0 + ch);
        }
        __syncthreads();
#pragma unroll
        for (int kk = 0; kk < 64; kk += 32) {
            bf16x8 ah[4], al[4], bb[4];
#pragma unroll
            for (int mt = 0; mt < 4; mt++) {
                ah[mt] = *(const bf16x8*)&Ah[wm * 64 + mt * 16 + l15][kk + hi * 8];
                al[mt] = *(const bf16x8*)&Al[wm * 64 + mt * 16 + l15][kk + hi * 8];
            }
#pragma unroll
            for (int nt = 0; nt < 4; nt++)
                bb[nt] = *(const bf16x8*)&Bs[wn * 64 + nt * 16 + l15][kk + hi * 8];
#pragma unroll
            for (int mt = 0; mt < 4; mt++)
#pragma unroll
                for (int nt = 0; nt < 4; nt++) {
                    acc[mt][nt] = mfma16(ah[mt], bb[nt], acc[mt][nt]);
                    acc[mt][nt] = mfma16(al[mt], bb[nt], acc[mt][nt]);
                }
        }
        __syncthreads();
    }

#pragma unroll
    for (int mt = 0; mt < 4; mt++)
#pragma unroll
        for (int nt = 0; nt < 4; nt++) {
            int n = bn + wn * 64 + nt * 16 + l15;
            float bs = bias[n];
#pragma unroll
            for (int r = 0; r < 4; r++) {
                int m = bm + wm * 64 + mt * 16 + hi * 4 + r;
                out[(size_t)m * 256 + n] = tanhf(acc[mt][nt][r] + bs);
            }
        }
}

// ---------------------------------------------------------------------------
// gi GEMM: 128x64 tile, K=1088, split-A AND split-B, 3-term MFMA.
// Rows t-major m = tt*32 + b; A = [ef_c | eb_c | sig*sigW+sigB] (fp32).
// out fp32 gi, ldc=1536, bias = bih folded.
// ---------------------------------------------------------------------------
__global__ __launch_bounds__(256) void gemm2_k(
    const float* __restrict__ ef, const float* __restrict__ eb,
    const float* __restrict__ sig, const float* __restrict__ sigW,
    const float* __restrict__ sigB, const float* __restrict__ W,
    const float* __restrict__ bias, float* __restrict__ out, int t0, int TC) {
    __shared__ bf16 Ah[128][72], Al[128][72];  // 36864 B
    __shared__ bf16 Bh[64][72], Bl[64][72];    // 18432 B

    const int tid = threadIdx.x;
    const int lane = tid & 63, wv = tid >> 6;
    const int wm = wv & 1, wn = wv >> 1;
    const int l15 = lane & 15, hi = lane >> 4;
    const int bm = blockIdx.x * 128, bn = blockIdx.y * 64;
    const int ch = (tid & 7) * 8, arow = tid >> 3;

    f32x4 acc[4][2] = {};
    int rb[4];
    float sigv[4];
#pragma unroll
    for (int i = 0; i < 4; i++) {
        int m = bm + arow + 32 * i;
        int tt = m >> 5, b = m & 31;
        rb[i] = b * TC + tt;
        sigv[i] = sig[b * TLEN + t0 + tt];
    }

    for (int k0 = 0; k0 < 1088; k0 += 64) {
#pragma unroll
        for (int i = 0; i < 4; i++) {
            int row = arow + 32 * i;
            int k = k0 + ch;
            f32x4 va, vb;
            if (k < 512) {
                va = *(const f32x4*)(ef + (size_t)rb[i] * 512 + k);
                vb = *(const f32x4*)(ef + (size_t)rb[i] * 512 + k + 4);
            } else if (k < 1024) {
                va = *(const f32x4*)(eb + (size_t)rb[i] * 512 + (k - 512));
                vb = *(const f32x4*)(eb + (size_t)rb[i] * 512 + (k - 512) + 4);
            } else {
                f32x4 w0 = *(const f32x4*)(sigW + ch);
                f32x4 w1 = *(const f32x4*)(sigW + ch + 4);
                f32x4 b0 = *(const f32x4*)(sigB + ch);
                f32x4 b1 = *(const f32x4*)(sigB + ch + 4);
                float s = sigv[i];
#pragma unroll
                for (int j = 0; j < 4; j++) {
                    va[j] = s * w0[j] + b0[j];
                    vb[j] = s * w1[j] + b1[j];
                }
            }
            bf16x8 vh, vl;
            splitv(va, vb, vh, vl);
            *(bf16x8*)&Ah[row][ch] = vh;
            *(bf16x8*)&Al[row][ch] = vl;
        }
#pragma unroll
        for (int i = 0; i < 2; i++) {
            int row = arow + 32 * i;  // 0..63
            const float* src = W + (size_t)(bn + row) * 1088 + k0 + ch;
            f32x4 va = *(const f32x4*)src;
            f32x4 vb = *(const f32x4*)(src + 4);
            bf16x8 vh, vl;
            splitv(va, vb, vh, vl);
            *(bf16x8*)&Bh[row][ch] = vh;
            *(bf16x8*)&Bl[row][ch] = vl;
        }
        __syncthreads();
#pragma unroll
        for (int kk = 0; kk < 64; kk += 32) {
            bf16x8 ah[4], al[4], bh[2], bl[2];
#pragma unroll
            for (int mt = 0; mt < 4; mt++) {
                ah[mt] = *(const bf16x8*)&Ah[wm * 64 + mt * 16 + l15][kk + hi * 8];
                al[mt] = *(const bf16x8*)&Al[wm * 64 + mt * 16 + l15][kk + hi * 8];
            }
#pragma unroll
            for (int nt = 0; nt < 2; nt++) {
                bh[nt] = *(const bf16x8*)&Bh[wn * 32 + nt * 16 + l15][kk + hi * 8];
                bl[nt] = *(const bf16x8*)&Bl[wn * 32 + nt * 16 + l15][kk + hi * 8];
            }
#pragma unroll
            for (int mt = 0; mt < 4; mt++)
#pragma unroll
                for (int nt = 0; nt < 2; nt++) {
                    acc[mt][nt] = mfma16(ah[mt], bh[nt], acc[mt][nt]);
                    acc[mt][nt] = mfma16(al[mt], bh[nt], acc[mt][nt]);
                    acc[mt][nt] = mfma16(ah[mt], bl[nt], acc[mt][nt]);
                }
        }
        __syncthreads();
    }

#pragma unroll
    for (int mt = 0; mt < 4; mt++)
#pragma unroll
        for (int nt = 0; nt < 2; nt++) {
            int n = bn + wn * 32 + nt * 16 + l15;
            float bs = bias[n];
#pragma unroll
            for (int r = 0; r < 4; r++) {
                int m = bm + wm * 64 + mt * 16 + hi * 4 + r;
                out[(size_t)m * 1536 + n] = acc[mt][nt][r] + bs;
            }
        }
}

// ---------------------------------------------------------------------------
// Pre-split concatenated encoder weights [Wih | Whh] (both dirs) into
// bf16 hi/lo. Layout: row (s*512 + j), k in 0..767 (k<256 = Wih, else Whh).
// out: [dir][hi,lo][1536*768] bf16. Bit-identical to in-kernel splitv.
// ---------------------------------------------------------------------------
__global__ __launch_bounds__(256) void wsplit_k(
    const float* __restrict__ fWih, const float* __restrict__ fWhh,
    const float* __restrict__ bWih, const float* __restrict__ bWhh,
    bf16* __restrict__ out) {
    const int idx = (blockIdx.x * 256 + threadIdx.x) * 8;  // grid.x=576
    const int dir = blockIdx.y;
    const int row = idx / WROW, k = idx - row * WROW;
    const float* src = (k < 256)
                           ? ((dir ? bWih : fWih) + (size_t)row * 256 + k)
                           : ((dir ? bWhh : fWhh) + (size_t)row * 512 + (k - 256));
    bf16* oh = out + (size_t)dir * 2 * WELEM;
    bf16* ol = oh + WELEM;
    f32x4 a = *(const f32x4*)src;
    f32x4 b = *(const f32x4*)(src + 4);
    bf16x8 vh, vl;
    splitv(a, b, vh, vl);
    *(bf16x8*)(oh + idx) = vh;
    *(bf16x8*)(ol + idx) = vl;
}

// ---------------------------------------------------------------------------
// Encoder GRU step (R9): pipelined kb loop. Double-buffered LDS; per iter:
// issue kb+1 global loads (A fp32 + pre-split B bf16) into regs, stage kb
// (splitv A; copy B), then RAW barrier (sched_barrier(0) + lgkmcnt(0) +
// s_barrier + sched_barrier(0)) -- no vmcnt drain, so kb+1 loads stay in
// flight across the barrier and their latency hides under kb's MFMA.
// One barrier per iteration (dbuf read/write hazard separated by >=1 bar).
// ---------------------------------------------------------------------------
__global__ __launch_bounds__(256) void enc_step_k(
    int step, int TC, const float* __restrict__ hpre, float* __restrict__ efb,
    float* __restrict__ ebb, const bf16* __restrict__ wsp,
    const float* __restrict__ fbih, const float* __restrict__ fbhh,
    const float* __restrict__ bbih, const float* __restrict__ bbhh) {
    __shared__ bf16 As[2][32][72], Alo[2][32][72];  // 18432 B
    __shared__ bf16 Bs[2][96][72], Blo[2][96][72];  // 55296 B

    const int dir = blockIdx.z;
    const bf16* Whi = wsp + (size_t)dir * 2 * WELEM;
    const bf16* Wlg = Whi + WELEM;
    const float* bih = dir ? bbih : fbih;
    const float* bhh = dir ? bbhh : fbhh;
    float* outb = dir ? ebb : efb;
    const int bsrc = dir ? (31 - step) : step;
    const int prevb = dir ? (32 - step) : (step - 1);

    const int tid = threadIdx.x;
    const int lane = tid & 63, wv = tid >> 6;
    const int mt = wv & 1, jt = wv >> 1;
    const int l15 = lane & 15, hi = lane >> 4;
    const int mtile = blockIdx.x, jtile = blockIdx.y;
    const int ch = (tid & 7) * 8, arow = tid >> 3;

    // A source row (constant across kb)
    const int trow = mtile * 32 + arow;
    const int tcl = trow < TC ? trow : TC - 1;
    const float* aph = hpre + ((size_t)bsrc * TC + tcl) * 256;  // + k0 + ch
    const float* apo = outb + ((size_t)prevb * TC + tcl) * 512; // + (k0-256) + ch

    // B staging map: 3 bf16x8 (hi) + 3 (lo) per thread per kb
    int bro[3], bkc[3];
    size_t bsr[3];
#pragma unroll
    for (int i = 0; i < 3; i++) {
        int v = tid + 256 * i;
        bro[i] = v >> 3;            // 0..95
        bkc[i] = (v & 7) * 8;       // 0..56
        bsr[i] = (size_t)((bro[i] >> 5) * 512 + jtile * 32 + (bro[i] & 31)) * WROW +
                 bkc[i];
    }

    const int nblocks = (step == 0) ? 4 : 12;

    f32x4 acc_r = {}, acc_z = {}, acc_in = {}, acc_hn = {};

    // prologue: load kb=0 (k0=0 < 256 always -> A from hpre)
    f32x4 vaC = *(const f32x4*)(aph + ch);
    f32x4 vbC = *(const f32x4*)(aph + ch + 4);
    bf16x8 bhC0 = *(const bf16x8*)(Whi + bsr[0]);
    bf16x8 bhC1 = *(const bf16x8*)(Whi + bsr[1]);
    bf16x8 bhC2 = *(const bf16x8*)(Whi + bsr[2]);
    bf16x8 blC0 = *(const bf16x8*)(Wlg + bsr[0]);
    bf16x8 blC1 = *(const bf16x8*)(Wlg + bsr[1]);
    bf16x8 blC2 = *(const bf16x8*)(Wlg + bsr[2]);

    for (int kb = 0; kb < nblocks; kb++) {
        const int buf = kb & 1;
        const int k0 = kb * 64;

        // issue next-iteration loads (stay in flight across the raw barrier)
        f32x4 vaN = {}, vbN = {};
        bf16x8 bhN0 = {}, bhN1 = {}, bhN2 = {}, blN0 = {}, blN1 = {}, blN2 = {};
        if (kb + 1 < nblocks) {
            int k0n = k0 + 64;
            const float* asrc =
                (k0n < 256) ? (aph + k0n + ch) : (apo + (k0n - 256) + ch);
            vaN = *(const f32x4*)asrc;
            vbN = *(const f32x4*)(asrc + 4);
            bhN0 = *(const bf16x8*)(Whi + bsr[0] + k0n);
            bhN1 = *(const bf16x8*)(Whi + bsr[1] + k0n);
            bhN2 = *(const bf16x8*)(Whi + bsr[2] + k0n);
            blN0 = *(const bf16x8*)(Wlg + bsr[0] + k0n);
            blN1 = *(const bf16x8*)(Wlg + bsr[1] + k0n);
            blN2 = *(const bf16x8*)(Wlg + bsr[2] + k0n);
        }

        // stage current kb -> LDS[buf]
        {
            bf16x8 vh, vl;
            splitv(vaC, vbC, vh, vl);
            *(bf16x8*)&As[buf][arow][ch] = vh;
            *(bf16x8*)&Alo[buf][arow][ch] = vl;
            *(bf16x8*)&Bs[buf][bro[0]][bkc[0]] = bhC0;
            *(bf16x8*)&Bs[buf][bro[1]][bkc[1]] = bhC1;
            *(bf16x8*)&Bs[buf][bro[2]][bkc[2]] = bhC2;
            *(bf16x8*)&Blo[buf][bro[0]][bkc[0]] = blC0;
            *(bf16x8*)&Blo[buf][bro[1]][bkc[1]] = blC1;
            *(bf16x8*)&Blo[buf][bro[2]][bkc[2]] = blC2;
        }
        // raw barrier: drain LDS writes (lgkm) but NOT the in-flight vmem
        __builtin_amdgcn_sched_barrier(0);
        asm volatile("s_waitcnt lgkmcnt(0)" ::: "memory");
        __builtin_amdgcn_s_barrier();
        __builtin_amdgcn_sched_barrier(0);

        // MFMA on LDS[buf]
#pragma unroll
        for (int kk = 0; kk < 64; kk += 32) {
            bf16x8 a = *(const bf16x8*)&As[buf][mt * 16 + l15][kk + hi * 8];
            bf16x8 alo = *(const bf16x8*)&Alo[buf][mt * 16 + l15][kk + hi * 8];
            bf16x8 brh = *(const bf16x8*)&Bs[buf][jt * 16 + l15][kk + hi * 8];
            bf16x8 brl = *(const bf16x8*)&Blo[buf][jt * 16 + l15][kk + hi * 8];
            bf16x8 bzh = *(const bf16x8*)&Bs[buf][32 + jt * 16 + l15][kk + hi * 8];
            bf16x8 bzl = *(const bf16x8*)&Blo[buf][32 + jt * 16 + l15][kk + hi * 8];
            bf16x8 bnh = *(const bf16x8*)&Bs[buf][64 + jt * 16 + l15][kk + hi * 8];
            bf16x8 bnl = *(const bf16x8*)&Blo[buf][64 + jt * 16 + l15][kk + hi * 8];
            acc_r = mfma16(a, brh, acc_r);
            acc_r = mfma16(alo, brh, acc_r);
            acc_r = mfma16(a, brl, acc_r);
            acc_z = mfma16(a, bzh, acc_z);
            acc_z = mfma16(alo, bzh, acc_z);
            acc_z = mfma16(a, bzl, acc_z);
            if (k0 < 256) {
                acc_in = mfma16(a, bnh, acc_in);
                acc_in = mfma16(alo, bnh, acc_in);
                acc_in = mfma16(a, bnl, acc_in);
            } else {
                acc_hn = mfma16(a, bnh, acc_hn);
                acc_hn = mfma16(alo, bnh, acc_hn);
                acc_hn = mfma16(a, bnl, acc_hn);
            }
        }

        // rotate prefetched registers
        vaC = vaN; vbC = vbN;
        bhC0 = bhN0; bhC1 = bhN1; bhC2 = bhN2;
        blC0 = blN0; blC1 = blN1; blC2 = blN2;
    }

    int j = jtile * 32 + jt * 16 + l15;
    float bir = bih[j] + bhh[j];
    float biz = bih[512 + j] + bhh[512 + j];
    float bin = bih[1024 + j];
    float bhn = bhh[1024 + j];
#pragma unroll
    for (int r = 0; r < 4; r++) {
        int trw = mtile * 32 + mt * 16 + hi * 4 + r;
        if (trw < TC) {
            float rr = sigm(acc_r[r] + bir);
            float zz = sigm(acc_z[r] + biz);
            float nn = tanhf(acc_in[r] + bin + rr * (acc_hn[r] + bhn));
            float hp = (step > 0) ? outb[((size_t)prevb * TC + trw) * 512 + j] : 0.f;
            outb[((size_t)bsrc * TC + trw) * 512 + j] = (1.f - zz) * nn + zz * hp;
        }
    }
}

// ---------------------------------------------------------------------------
// Persistent decoder chunk (R8, best measured). BOTH decoders per launch,
// 32 WGs: d = blockIdx.x>>4, c = (blockIdx.x>>3)&1 (16-row chain),
// g = blockIdx.x&7 (64-col group; cols j = g*64 + wv*16 + l15).
// Fan-in 8 per (decoder, chain); Wf[3][16] bf16-hi in regs; H fp32; relaxed
// agent atomics. Producer: sc H stores + syncthreads (vmcnt drain) + tid0
// relaxed flag store. Consumer: wave0 lanes 0-7 poll + syncthreads.
// ---------------------------------------------------------------------------
__global__ __launch_bounds__(256, 1) void dec_k(
    const float* __restrict__ giF, const float* __restrict__ giR,
    const float* __restrict__ WhhF, const float* __restrict__ WhhR,
    const float* __restrict__ bhhF, const float* __restrict__ bhhR,
    float* __restrict__ HcurF, float* __restrict__ HcurR,
    const float* __restrict__ HprevF, const float* __restrict__ HprevR,
    int* __restrict__ flags, int t0, int TC) {
    const int d = blockIdx.x >> 4;
    const int c = (blockIdx.x >> 3) & 1;
    const int g = blockIdx.x & 7;
    const float* gi = d ? giR : giF;
    const float* Whh = d ? WhhR : WhhF;
    const float* bhh = d ? bhhR : bhhF;
    float* Hcur = d ? HcurR : HcurF;
    const float* Hprev = d ? HprevR : HprevF;
    int* flg = flags + d * 32 + c * 8;  // 8 flags per (decoder, chain)

    const int tid = threadIdx.x;
    const int lane = tid & 63, wv = tid >> 6;
    const int l15 = lane & 15, hi = lane >> 4;
    const int j_abs = g * 64 + wv * 16 + l15;  // 64 cols per WG, 16 per wave
    const int brow = c * 16;                   // chain's base batch row

    bf16x8 Wf[3][16];
#pragma unroll
    for (int s = 0; s < 3; s++)
#pragma unroll
        for (int kb = 0; kb < 16; kb++)
            Wf[s][kb] = ld8f(Whh + (size_t)(s * 512 + j_abs) * 512 + kb * 32 + hi * 8);

    const float bhr = bhh[j_abs];
    const float bhz = bhh[512 + j_abs];
    const float bhn = bhh[1024 + j_abs];

    float hpreg[4] = {0.f, 0.f, 0.f, 0.f};

    for (int tt = 0; tt < TC; tt++) {
        const int t = t0 + tt;
        float gr[4], gz[4], gn[4];
#pragma unroll
        for (int r = 0; r < 4; r++) {
            int b = brow + hi * 4 + r;
            const float* gp = gi + ((size_t)tt * BATCH + b) * 1536 + j_abs;
            gr[r] = gp[0];
            gz[r] = gp[512];
            gn[r] = gp[1024];
        }

        f32x4 ar = {}, az = {}, an = {};
        float hp[4] = {0.f, 0.f, 0.f, 0.f};
        if (t > 0) {
            const float* base;
            if (tt > 0) {
                // wait until this chain's 8 producer WGs published step t-1
                if (wv == 0 && lane < 8) {
                    while (__hip_atomic_load(&flg[lane], __ATOMIC_RELAXED,
                                             __HIP_MEMORY_SCOPE_AGENT) < t)
                        __builtin_amdgcn_s_sleep(1);
                }
                __syncthreads();
                base = Hcur + (size_t)(tt - 1) * BATCH * 512;
            } else {
                base = Hprev + (size_t)(TC - 1) * BATCH * 512;
            }
            // A fragment: row = brow + l15 (chain's 16 rows), k = kb*32+hi*8
            const float* ap = base + (size_t)(brow + l15) * 512 + hi * 8;
#pragma unroll
            for (int half = 0; half < 2; half++) {
                f32x4 raw[8][2];
#pragma unroll
                for (int q = 0; q < 8; q++) {
                    int kb = half * 8 + q;
                    raw[q][0] = cld_f32x4(ap + kb * 32);
                    raw[q][1] = cld_f32x4(ap + kb * 32 + 4);
                }
#pragma unroll
                for (int q = 0; q < 8; q++) {
                    int kb = half * 8 + q;
                    bf16x8 ah, al;
                    splitv(raw[q][0], raw[q][1], ah, al);
                    ar = mfma16(ah, Wf[0][kb], ar);
                    ar = mfma16(al, Wf[0][kb], ar);
                    az = mfma16(ah, Wf[1][kb], az);
                    az = mfma16(al, Wf[1][kb], az);
                    an = mfma16(ah, Wf[2][kb], an);
                    an = mfma16(al, Wf[2][kb], an);
                }
            }
            if (tt > 0) {
#pragma unroll
                for (int r = 0; r < 4; r++) hp[r] = hpreg[r];
            } else {
#pragma unroll
                for (int r = 0; r < 4; r++) {
                    int b = brow + hi * 4 + r;
                    hp[r] = cld_f32(base + (size_t)b * 512 + j_abs);
                }
            }
        }
#pragma unroll
        for (int r = 0; r < 4; r++) {
            int b = brow + hi * 4 + r;
            float rr = sigm(gr[r] + ar[r] + bhr);
            float zz = sigm(gz[r] + az[r] + bhz);
            float nn = tanhf(gn[r] + rr * (an[r] + bhn));
            float hnew = (1.f - zz) * nn + zz * hp[r];
            cst_f32(&Hcur[((size_t)tt * BATCH + b) * 512 + j_abs], hnew);
            hpreg[r] = hnew;
        }
        // syncthreads emits s_waitcnt vmcnt(0) before s_barrier: all waves'
        // coherent H stores are ACKed at the LLC. tid0 then publishes step t.
        __syncthreads();
        if (tid == 0)
            __hip_atomic_store(&flg[g], t + 1, __ATOMIC_RELAXED,
                               __HIP_MEMORY_SCOPE_AGENT);
    }
}

// ---------------------------------------------------------------------------
// Head: out[b*800 + t0 + tt] = dot(W, H[tt*32+b][:]) + bias  (fp32)
// ---------------------------------------------------------------------------
__global__ __launch_bounds__(256) void post_k(
    const float* __restrict__ H, const float* __restrict__ W,
    const float* __restrict__ bs, float* __restrict__ out, int t0) {
    const int wv = threadIdx.x >> 6, lane = threadIdx.x & 63;
    const int row = blockIdx.x * 4 + wv;
    const int tt = row >> 5, b = row & 31;
    const float bias = bs[0];
    const float* hp = H + (size_t)row * 512 + lane * 8;
    f32x4 h0 = *(const f32x4*)hp;
    f32x4 h1 = *(const f32x4*)(hp + 4);
    f32x4 w0 = *(const f32x4*)(W + lane * 8);
    f32x4 w1 = *(const f32x4*)(W + lane * 8 + 4);
    float s = 0.f;
#pragma unroll
    for (int i = 0; i < 4; i++) s += h0[i] * w0[i] + h1[i] * w1[i];
#pragma unroll
    for (int off = 32; off > 0; off >>= 1) s += __shfl_down(s, off);
    if (lane == 0) out[b * TLEN + t0 + tt] = s + bias;
}

__global__ void zero_k(int* __restrict__ flags) {
    int i = blockIdx.x * 256 + threadIdx.x;
    if (i < 2 * TLEN)
        __hip_atomic_store(&flags[i], 0, __ATOMIC_RELAXED,
                           __HIP_MEMORY_SCOPE_AGENT);
}

// ---------------------------------------------------------------------------
extern "C" void kernel_launch(void* const* d_in, const int* in_sizes, int n_in,
                              void* d_out, int out_size, void* d_ws, size_t ws_size,
                              hipStream_t stream) {
    const int* note = (const int*)d_in[0];
    const float* f0_prev = (const float*)d_in[1];
    const float* rmse_prev = (const float*)d_in[2];
    const float* note_emb = (const float*)d_in[3];
    const float* f0_W = (const float*)d_in[4];
    const float* f0_b = (const float*)d_in[5];
    const float* rmse_W = (const float*)d_in[6];
    const float* rmse_b = (const float*)d_in[7];
    const float* pre1_W = (const float*)d_in[8];
    const float* pre1_b = (const float*)d_in[9];
    const float* pre2_W = (const float*)d_in[10];
    const float* pre2_b = (const float*)d_in[11];
    const float* encf_Wih = (const float*)d_in[12];
    const float* encf_Whh = (const float*)d_in[13];
    const float* encf_bih = (const float*)d_in[14];
    const float* encf_bhh = (const float*)d_in[15];
    const float* encb_Wih = (const float*)d_in[16];
    const float* encb_Whh = (const float*)d_in[17];
    const float* encb_bih = (const float*)d_in[18];
    const float* encb_bhh = (const float*)d_in[19];
    const float* decf_Wih = (const float*)d_in[20];
    const float* decf_Whh = (const float*)d_in[21];
    const float* decf_bih = (const float*)d_in[22];
    const float* decf_bhh = (const float*)d_in[23];
    const float* decr_Wih = (const float*)d_in[24];
    const float* decr_Whh = (const float*)d_in[25];
    const float* decr_bih = (const float*)d_in[26];
    const float* decr_bhh = (const float*)d_in[27];
    const float* postf_W = (const float*)d_in[28];
    const float* postf_b = (const float*)d_in[29];
    const float* postr_W = (const float*)d_in[30];
    const float* postr_b = (const float*)d_in[31];
    float* out = (float*)d_out;  // reference output dtype is float32

    // --- choose chunk size TC from ws_size (multiple of 4, divides 800) ---
    // per-TC bytes: ef/eb 2*65536 + gi 2*196608 + H rings 2*slots*65536,
    // plus constant 9.44 MB pre-split encoder weights.
    const size_t WSPB = (size_t)4 * WELEM * 2;  // 9,437,184 B
    const int tcs[9] = {800, 400, 200, 100, 80, 40, 20, 8, 4};
    int TC = 4;
    for (int i = 0; i < 9; i++) {
        int tc = tcs[i];
        int slots = (tc == TLEN) ? 1 : 2;
        size_t need = (size_t)(2 * 65536 + 2 * 196608 + 2 * slots * 65536) * tc +
                      WSPB + 131072;
        if (ws_size >= need) { TC = tc; break; }
    }
    const int NC = TLEN / TC;
    const int slots = (NC == 1) ? 1 : 2;

    char* ws = (char*)d_ws;
    size_t off = 0;
    auto carve = [&](size_t bytes) {
        void* p = ws + off;
        off += (bytes + 255) & ~(size_t)255;
        return p;
    };
    const size_t slotB = (size_t)65536 * TC;  // TC*32*512*4 bytes (fp32)
    float* ef_c = (float*)carve(slotB);
    float* eb_c = (float*)carve(slotB);
    float* giF_c = (float*)carve((size_t)196608 * TC);
    float* giR_c = (float*)carve((size_t)196608 * TC);
    float* ringF = (float*)carve(slotB * slots);
    float* ringR = (float*)carve(slotB * slots);
    bf16* wsp = (bf16*)carve(WSPB);  // [2 dirs][hi,lo][1536*768] bf16
    int* flags = (int*)carve(2 * TLEN * 4);
    // prenet temporaries alias giF_c (dead once gi is computed): fp32
    float* t1_c = giF_c;                         // 32*TC x 256 fp32
    float* hpre_c = giF_c + (size_t)8192 * TC;   // 32*TC x 256 fp32

    zero_k<<<dim3(7), 256, 0, stream>>>(flags);
    wsplit_k<<<dim3(576, 2), 256, 0, stream>>>(encf_Wih, encf_Whh, encb_Wih,
                                               encb_Whh, wsp);

    const size_t slotE = (size_t)TC * BATCH * 512;

    for (int c = 0; c < NC; c++) {
        const int t0 = c * TC;
        const int mg = TC * 32 / 128;  // 4 | TC -> exact

        gemm01_k<0><<<dim3(mg, 2), 256, 0, stream>>>(note, note_emb, pre1_W, pre1_b,
                                                     t1_c, t0, TC);
        gemm01_k<1><<<dim3(mg, 2), 256, 0, stream>>>(nullptr, t1_c, pre2_W, pre2_b,
                                                     hpre_c, t0, TC);
        const int etiles = (TC + 31) / 32;
        for (int i = 0; i < 32; i++)
            enc_step_k<<<dim3(etiles, 16, 2), 256, 0, stream>>>(
                i, TC, hpre_c, ef_c, eb_c, wsp, encf_bih, encf_bhh, encb_bih,
                encb_bhh);

        // gi for both decoders (gemm2 writes giF after hpre/t1 are dead)
        gemm2_k<<<dim3(mg, 24), 256, 0, stream>>>(ef_c, eb_c, f0_prev, f0_W, f0_b,
                                                  decf_Wih, decf_bih, giF_c, t0, TC);
        gemm2_k<<<dim3(mg, 24), 256, 0, stream>>>(ef_c, eb_c, rmse_prev, rmse_W,
                                                  rmse_b, decr_Wih, decr_bih, giR_c,
                                                  t0, TC);

        float* HcurF = ringF + (size_t)(c & (slots - 1)) * slotE;
        const float* HprevF = ringF + (size_t)((c - 1) & (slots - 1)) * slotE;
        float* HcurR = ringR + (size_t)(c & (slots - 1)) * slotE;
        const float* HprevR = ringR + (size_t)((c - 1) & (slots - 1)) * slotE;

        // BOTH decoders in one launch: 32 WGs, d = bid>>4, chain = (bid>>3)&1
        dec_k<<<dim3(32), 256, 0, stream>>>(giF_c, giR_c, decf_Whh, decr_Whh,
                                            decf_bhh, decr_bhh, HcurF, HcurR,
                                            HprevF, HprevR, flags, t0, TC);

        post_k<<<dim3(TC * 32 / 4), 256, 0, stream>>>(HcurF, postf_W, postf_b,
                                                      out, t0);
        post_k<<<dim3(TC * 32 / 4), 256, 0, stream>>>(HcurR, postr_W, postr_b,
                                                      out + BT, t0);
    }
    (void)in_sizes; (void)n_in; (void)out_size; (void)ws_size;
}

// Round 10
// 10721.266 us; speedup vs baseline: 1.9905x; 1.0354x over previous
//
#include <hip/hip_runtime.h>
#include <hip/hip_bf16.h>

// ---------------------------------------------------------------------------
// Acoustic model: embed+prenet -> bi-GRU encoder (scan over B=32, batch T=800)
// -> 2x GRU decoders (scan over T=800, batch B=32) -> linear heads.
// OUTPUT IS FLOAT32. Precision: activations fp32; MFMA bf16 hi/lo split.
// R1: both decoders in ONE dec_k launch -> latency chains overlap.
// R2: WG-flag fence-free handshake. R8: dec 2x16-row chains, fan-in 8
//     (dec step period ~9.3us = intrinsic LLC chain floor).
// R9: enc_step kb-loop pipelined (pre-split weights, dbuf LDS, raw barrier,
//     1-deep reg prefetch). Best: 11100us.
// R10: enc_step grid XCD-swizzle. Old grid put the 7 mtile-WGs sharing a
//     jtile B-slice on 7 DIFFERENT XCDs -> per-XCD L2 duplication, 37MB
//     HBM fetch per launch (4x unique). New 1-D grid bid = (jtile+16*dir)
//     + 32*mtile makes XCD(bid%8) constant across mtiles of a slice ->
//     per-XCD weight set 1.2MB, L2-resident across all launches.
// ---------------------------------------------------------------------------

typedef __bf16 bf16;
typedef bf16 bf16x8 __attribute__((ext_vector_type(8)));
typedef float f32x4 __attribute__((ext_vector_type(4)));
typedef float f32x2 __attribute__((ext_vector_type(2)));

#define BATCH 32
#define TLEN 800
#define BT (BATCH * TLEN)
#define WROW 768           // concatenated K: 256 (Wih) + 512 (Whh)
#define WELEM 1179648      // 1536 * 768 per dir per (hi|lo)

__device__ __forceinline__ float bf2f(bf16 v) {
    unsigned short u = __builtin_bit_cast(unsigned short, v);
    unsigned int x = ((unsigned int)u) << 16;
    return __builtin_bit_cast(float, x);
}
__device__ __forceinline__ bf16 f2bf(float f) {
    unsigned int x = __builtin_bit_cast(unsigned int, f);
    unsigned int r = (x + 0x7FFFu + ((x >> 16) & 1u)) >> 16;
    return __builtin_bit_cast(bf16, (unsigned short)r);
}
__device__ __forceinline__ bf16x8 ld8f(const float* p) {
    f32x4 a = *(const f32x4*)p;
    f32x4 b = *(const f32x4*)(p + 4);
    bf16x8 r;
#pragma unroll
    for (int i = 0; i < 4; i++) {
        r[i] = f2bf(a[i]);
        r[i + 4] = f2bf(b[i]);
    }
    return r;
}
// split 8 floats into hi + lo bf16 (hi = rne(v), lo = rne(v - hi))
__device__ __forceinline__ void splitv(f32x4 a, f32x4 b, bf16x8& vh, bf16x8& vl) {
#pragma unroll
    for (int j = 0; j < 4; j++) {
        bf16 h0 = f2bf(a[j]);
        vh[j] = h0;
        vl[j] = f2bf(a[j] - bf2f(h0));
        bf16 h1 = f2bf(b[j]);
        vh[j + 4] = h1;
        vl[j + 4] = f2bf(b[j] - bf2f(h1));
    }
}
__device__ __forceinline__ f32x4 mfma16(bf16x8 a, bf16x8 b, f32x4 c) {
    return __builtin_amdgcn_mfma_f32_16x16x32_bf16(a, b, c, 0, 0, 0);
}
__device__ __forceinline__ float sigm(float x) { return 1.f / (1.f + __expf(-x)); }

// --- LLC-coherent (agent-scope, relaxed) access helpers for cross-WG data ---
__device__ __forceinline__ void cst_f32(float* p, float v) {
    __hip_atomic_store((unsigned int*)p, __builtin_bit_cast(unsigned int, v),
                       __ATOMIC_RELAXED, __HIP_MEMORY_SCOPE_AGENT);
}
__device__ __forceinline__ float cld_f32(const float* p) {
    unsigned int u = __hip_atomic_load((const unsigned int*)p, __ATOMIC_RELAXED,
                                       __HIP_MEMORY_SCOPE_AGENT);
    return __builtin_bit_cast(float, u);
}
__device__ __forceinline__ f32x4 cld_f32x4(const float* p) {
    unsigned long long a = __hip_atomic_load((const unsigned long long*)p,
                                             __ATOMIC_RELAXED,
                                             __HIP_MEMORY_SCOPE_AGENT);
    unsigned long long b = __hip_atomic_load((const unsigned long long*)(p + 2),
                                             __ATOMIC_RELAXED,
                                             __HIP_MEMORY_SCOPE_AGENT);
    f32x2 fa = __builtin_bit_cast(f32x2, a);
    f32x2 fb = __builtin_bit_cast(f32x2, b);
    f32x4 r;
    r[0] = fa[0]; r[1] = fa[1]; r[2] = fb[0]; r[3] = fb[1];
    return r;
}

// ---------------------------------------------------------------------------
// Prenet GEMM, 128x128 tile, K=256, split-A (fp32 src), plain-B, tanh epilogue.
// Rows b-major m = b*TC + tt.
// MODE 0: A row = note_emb[note[b*800+t0+tt]]; MODE 1: A row = asrc + m*256.
// out fp32, ldc=256.
// ---------------------------------------------------------------------------
template <int MODE>
__global__ __launch_bounds__(256) void gemm01_k(
    const int* __restrict__ note, const float* __restrict__ asrc,
    const float* __restrict__ W, const float* __restrict__ bias,
    float* __restrict__ out, int t0, int TC) {
    __shared__ bf16 Ah[128][72], Al[128][72], Bs[128][72];  // 55296 B

    const int tid = threadIdx.x;
    const int lane = tid & 63, wv = tid >> 6;
    const int wm = wv & 1, wn = wv >> 1;
    const int l15 = lane & 15, hi = lane >> 4;
    const int bm = blockIdx.x * 128, bn = blockIdx.y * 128;
    const int ch = (tid & 7) * 8, arow = tid >> 3;

    f32x4 acc[4][4] = {};
    const float* ap[4];
    if (MODE == 0) {
        int zc = 0;
        for (int i = 0; i < 64; i++) zc += (note[2 * i + 1] == 0) ? 1 : 0;
        const bool n64 = (zc >= 60);
#pragma unroll
        for (int i = 0; i < 4; i++) {
            int m = bm + arow + 32 * i;
            int b = m / TC, tt = m - b * TC;
            int idx = b * TLEN + t0 + tt;
            int id = n64 ? note[2 * idx] : note[idx];
            id = id < 0 ? 0 : (id > 127 ? 127 : id);
            ap[i] = asrc + (size_t)id * 256;
        }
    } else {
#pragma unroll
        for (int i = 0; i < 4; i++) ap[i] = asrc + (size_t)(bm + arow + 32 * i) * 256;
    }

    for (int k0 = 0; k0 < 256; k0 += 64) {
#pragma unroll
        for (int i = 0; i < 4; i++) {
            int row = arow + 32 * i;
            f32x4 va = *(const f32x4*)(ap[i] + k0 + ch);
            f32x4 vb = *(const f32x4*)(ap[i] + k0 + ch + 4);
            bf16x8 vh, vl;
            splitv(va, vb, vh, vl);
            *(bf16x8*)&Ah[row][ch] = vh;
            *(bf16x8*)&Al[row][ch] = vl;
        }
#pragma unroll
        for (int i = 0; i < 4; i++) {
            int row = arow + 32 * i;
            *(bf16x8*)&Bs[row][ch] = ld8f(W + (size_t)(bn + row) * 256 + k0 + ch);
        }
        __syncthreads();
#pragma unroll
        for (int kk = 0; kk < 64; kk += 32) {
            bf16x8 ah[4], al[4], bb[4];
#pragma unroll
            for (int mt = 0; mt < 4; mt++) {
                ah[mt] = *(const bf16x8*)&Ah[wm * 64 + mt * 16 + l15][kk + hi * 8];
                al[mt] = *(const bf16x8*)&Al[wm * 64 + mt * 16 + l15][kk + hi * 8];
            }
#pragma unroll
            for (int nt = 0; nt < 4; nt++)
                bb[nt] = *(const bf16x8*)&Bs[wn * 64 + nt * 16 + l15][kk + hi * 8];
#pragma unroll
            for (int mt = 0; mt < 4; mt++)
#pragma unroll
                for (int nt = 0; nt < 4; nt++) {
                    acc[mt][nt] = mfma16(ah[mt], bb[nt], acc[mt][nt]);
                    acc[mt][nt] = mfma16(al[mt], bb[nt], acc[mt][nt]);
                }
        }
        __syncthreads();
    }

#pragma unroll
    for (int mt = 0; mt < 4; mt++)
#pragma unroll
        for (int nt = 0; nt < 4; nt++) {
            int n = bn + wn * 64 + nt * 16 + l15;
            float bs = bias[n];
#pragma unroll
            for (int r = 0; r < 4; r++) {
                int m = bm + wm * 64 + mt * 16 + hi * 4 + r;
                out[(size_t)m * 256 + n] = tanhf(acc[mt][nt][r] + bs);
            }
        }
}

// ---------------------------------------------------------------------------
// gi GEMM: 128x64 tile, K=1088, split-A AND split-B, 3-term MFMA.
// Rows t-major m = tt*32 + b; A = [ef_c | eb_c | sig*sigW+sigB] (fp32).
// out fp32 gi, ldc=1536, bias = bih folded.
// ---------------------------------------------------------------------------
__global__ __launch_bounds__(256) void gemm2_k(
    const float* __restrict__ ef, const float* __restrict__ eb,
    const float* __restrict__ sig, const float* __restrict__ sigW,
    const float* __restrict__ sigB, const float* __restrict__ W,
    const float* __restrict__ bias, float* __restrict__ out, int t0, int TC) {
    __shared__ bf16 Ah[128][72], Al[128][72];  // 36864 B
    __shared__ bf16 Bh[64][72], Bl[64][72];    // 18432 B

    const int tid = threadIdx.x;
    const int lane = tid & 63, wv = tid >> 6;
    const int wm = wv & 1, wn = wv >> 1;
    const int l15 = lane & 15, hi = lane >> 4;
    const int bm = blockIdx.x * 128, bn = blockIdx.y * 64;
    const int ch = (tid & 7) * 8, arow = tid >> 3;

    f32x4 acc[4][2] = {};
    int rb[4];
    float sigv[4];
#pragma unroll
    for (int i = 0; i < 4; i++) {
        int m = bm + arow + 32 * i;
        int tt = m >> 5, b = m & 31;
        rb[i] = b * TC + tt;
        sigv[i] = sig[b * TLEN + t0 + tt];
    }

    for (int k0 = 0; k0 < 1088; k0 += 64) {
#pragma unroll
        for (int i = 0; i < 4; i++) {
            int row = arow + 32 * i;
            int k = k0 + ch;
            f32x4 va, vb;
            if (k < 512) {
                va = *(const f32x4*)(ef + (size_t)rb[i] * 512 + k);
                vb = *(const f32x4*)(ef + (size_t)rb[i] * 512 + k + 4);
            } else if (k < 1024) {
                va = *(const f32x4*)(eb + (size_t)rb[i] * 512 + (k - 512));
                vb = *(const f32x4*)(eb + (size_t)rb[i] * 512 + (k - 512) + 4);
            } else {
                f32x4 w0 = *(const f32x4*)(sigW + ch);
                f32x4 w1 = *(const f32x4*)(sigW + ch + 4);
                f32x4 b0 = *(const f32x4*)(sigB + ch);
                f32x4 b1 = *(const f32x4*)(sigB + ch + 4);
                float s = sigv[i];
#pragma unroll
                for (int j = 0; j < 4; j++) {
                    va[j] = s * w0[j] + b0[j];
                    vb[j] = s * w1[j] + b1[j];
                }
            }
            bf16x8 vh, vl;
            splitv(va, vb, vh, vl);
            *(bf16x8*)&Ah[row][ch] = vh;
            *(bf16x8*)&Al[row][ch] = vl;
        }
#pragma unroll
        for (int i = 0; i < 2; i++) {
            int row = arow + 32 * i;  // 0..63
            const float* src = W + (size_t)(bn + row) * 1088 + k0 + ch;
            f32x4 va = *(const f32x4*)src;
            f32x4 vb = *(const f32x4*)(src + 4);
            bf16x8 vh, vl;
            splitv(va, vb, vh, vl);
            *(bf16x8*)&Bh[row][ch] = vh;
            *(bf16x8*)&Bl[row][ch] = vl;
        }
        __syncthreads();
#pragma unroll
        for (int kk = 0; kk < 64; kk += 32) {
            bf16x8 ah[4], al[4], bh[2], bl[2];
#pragma unroll
            for (int mt = 0; mt < 4; mt++) {
                ah[mt] = *(const bf16x8*)&Ah[wm * 64 + mt * 16 + l15][kk + hi * 8];
                al[mt] = *(const bf16x8*)&Al[wm * 64 + mt * 16 + l15][kk + hi * 8];
            }
#pragma unroll
            for (int nt = 0; nt < 2; nt++) {
                bh[nt] = *(const bf16x8*)&Bh[wn * 32 + nt * 16 + l15][kk + hi * 8];
                bl[nt] = *(const bf16x8*)&Bl[wn * 32 + nt * 16 + l15][kk + hi * 8];
            }
#pragma unroll
            for (int mt = 0; mt < 4; mt++)
#pragma unroll
                for (int nt = 0; nt < 2; nt++) {
                    acc[mt][nt] = mfma16(ah[mt], bh[nt], acc[mt][nt]);
                    acc[mt][nt] = mfma16(al[mt], bh[nt], acc[mt][nt]);
                    acc[mt][nt] = mfma16(ah[mt], bl[nt], acc[mt][nt]);
                }
        }
        __syncthreads();
    }

#pragma unroll
    for (int mt = 0; mt < 4; mt++)
#pragma unroll
        for (int nt = 0; nt < 2; nt++) {
            int n = bn + wn * 32 + nt * 16 + l15;
            float bs = bias[n];
#pragma unroll
            for (int r = 0; r < 4; r++) {
                int m = bm + wm * 64 + mt * 16 + hi * 4 + r;
                out[(size_t)m * 1536 + n] = acc[mt][nt][r] + bs;
            }
        }
}

// ---------------------------------------------------------------------------
// Pre-split concatenated encoder weights [Wih | Whh] (both dirs) into
// bf16 hi/lo. Layout: row (s*512 + j), k in 0..767 (k<256 = Wih, else Whh).
// out: [dir][hi,lo][1536*768] bf16. Bit-identical to in-kernel splitv.
// ---------------------------------------------------------------------------
__global__ __launch_bounds__(256) void wsplit_k(
    const float* __restrict__ fWih, const float* __restrict__ fWhh,
    const float* __restrict__ bWih, const float* __restrict__ bWhh,
    bf16* __restrict__ out) {
    const int idx = (blockIdx.x * 256 + threadIdx.x) * 8;  // grid.x=576
    const int dir = blockIdx.y;
    const int row = idx / WROW, k = idx - row * WROW;
    const float* src = (k < 256)
                           ? ((dir ? bWih : fWih) + (size_t)row * 256 + k)
                           : ((dir ? bWhh : fWhh) + (size_t)row * 512 + (k - 256));
    bf16* oh = out + (size_t)dir * 2 * WELEM;
    bf16* ol = oh + WELEM;
    f32x4 a = *(const f32x4*)src;
    f32x4 b = *(const f32x4*)(src + 4);
    bf16x8 vh, vl;
    splitv(a, b, vh, vl);
    *(bf16x8*)(oh + idx) = vh;
    *(bf16x8*)(ol + idx) = vl;
}

// ---------------------------------------------------------------------------
// Encoder GRU step (R10): R9's pipelined kb loop, with a 1-D XCD-swizzled
// grid: bid = (jtile + 16*dir) + 32*mtile. XCD = bid%8 is constant across
// the mtiles sharing a (jtile,dir) B-slice -> per-XCD weight working set
// ~1.2MB, L2-resident across launches (was 37MB HBM refetch per launch).
// ---------------------------------------------------------------------------
__global__ __launch_bounds__(256) void enc_step_k(
    int step, int TC, const float* __restrict__ hpre, float* __restrict__ efb,
    float* __restrict__ ebb, const bf16* __restrict__ wsp,
    const float* __restrict__ fbih, const float* __restrict__ fbhh,
    const float* __restrict__ bbih, const float* __restrict__ bbhh) {
    __shared__ bf16 As[2][32][72], Alo[2][32][72];  // 18432 B
    __shared__ bf16 Bs[2][96][72], Blo[2][96][72];  // 55296 B

    // XCD-swizzled decomposition: jd = bid&31 fixes XCD (bid%8) per slice
    const int bid = blockIdx.x;
    const int jd = bid & 31;
    const int mtile = bid >> 5;
    const int jtile = jd & 15;
    const int dir = jd >> 4;

    const bf16* Whi = wsp + (size_t)dir * 2 * WELEM;
    const bf16* Wlg = Whi + WELEM;
    const float* bih = dir ? bbih : fbih;
    const float* bhh = dir ? bbhh : fbhh;
    float* outb = dir ? ebb : efb;
    const int bsrc = dir ? (31 - step) : step;
    const int prevb = dir ? (32 - step) : (step - 1);

    const int tid = threadIdx.x;
    const int lane = tid & 63, wv = tid >> 6;
    const int mt = wv & 1, jt = wv >> 1;
    const int l15 = lane & 15, hi = lane >> 4;
    const int ch = (tid & 7) * 8, arow = tid >> 3;

    // A source row (constant across kb)
    const int trow = mtile * 32 + arow;
    const int tcl = trow < TC ? trow : TC - 1;
    const float* aph = hpre + ((size_t)bsrc * TC + tcl) * 256;  // + k0 + ch
    const float* apo = outb + ((size_t)prevb * TC + tcl) * 512; // + (k0-256) + ch

    // B staging map: 3 bf16x8 (hi) + 3 (lo) per thread per kb
    int bro[3], bkc[3];
    size_t bsr[3];
#pragma unroll
    for (int i = 0; i < 3; i++) {
        int v = tid + 256 * i;
        bro[i] = v >> 3;            // 0..95
        bkc[i] = (v & 7) * 8;       // 0..56
        bsr[i] = (size_t)((bro[i] >> 5) * 512 + jtile * 32 + (bro[i] & 31)) * WROW +
                 bkc[i];
    }

    const int nblocks = (step == 0) ? 4 : 12;

    f32x4 acc_r = {}, acc_z = {}, acc_in = {}, acc_hn = {};

    // prologue: load kb=0 (k0=0 < 256 always -> A from hpre)
    f32x4 vaC = *(const f32x4*)(aph + ch);
    f32x4 vbC = *(const f32x4*)(aph + ch + 4);
    bf16x8 bhC0 = *(const bf16x8*)(Whi + bsr[0]);
    bf16x8 bhC1 = *(const bf16x8*)(Whi + bsr[1]);
    bf16x8 bhC2 = *(const bf16x8*)(Whi + bsr[2]);
    bf16x8 blC0 = *(const bf16x8*)(Wlg + bsr[0]);
    bf16x8 blC1 = *(const bf16x8*)(Wlg + bsr[1]);
    bf16x8 blC2 = *(const bf16x8*)(Wlg + bsr[2]);

    for (int kb = 0; kb < nblocks; kb++) {
        const int buf = kb & 1;
        const int k0 = kb * 64;

        // issue next-iteration loads (stay in flight across the raw barrier)
        f32x4 vaN = {}, vbN = {};
        bf16x8 bhN0 = {}, bhN1 = {}, bhN2 = {}, blN0 = {}, blN1 = {}, blN2 = {};
        if (kb + 1 < nblocks) {
            int k0n = k0 + 64;
            const float* asrc =
                (k0n < 256) ? (aph + k0n + ch) : (apo + (k0n - 256) + ch);
            vaN = *(const f32x4*)asrc;
            vbN = *(const f32x4*)(asrc + 4);
            bhN0 = *(const bf16x8*)(Whi + bsr[0] + k0n);
            bhN1 = *(const bf16x8*)(Whi + bsr[1] + k0n);
            bhN2 = *(const bf16x8*)(Whi + bsr[2] + k0n);
            blN0 = *(const bf16x8*)(Wlg + bsr[0] + k0n);
            blN1 = *(const bf16x8*)(Wlg + bsr[1] + k0n);
            blN2 = *(const bf16x8*)(Wlg + bsr[2] + k0n);
        }

        // stage current kb -> LDS[buf]
        {
            bf16x8 vh, vl;
            splitv(vaC, vbC, vh, vl);
            *(bf16x8*)&As[buf][arow][ch] = vh;
            *(bf16x8*)&Alo[buf][arow][ch] = vl;
            *(bf16x8*)&Bs[buf][bro[0]][bkc[0]] = bhC0;
            *(bf16x8*)&Bs[buf][bro[1]][bkc[1]] = bhC1;
            *(bf16x8*)&Bs[buf][bro[2]][bkc[2]] = bhC2;
            *(bf16x8*)&Blo[buf][bro[0]][bkc[0]] = blC0;
            *(bf16x8*)&Blo[buf][bro[1]][bkc[1]] = blC1;
            *(bf16x8*)&Blo[buf][bro[2]][bkc[2]] = blC2;
        }
        // raw barrier: drain LDS writes (lgkm) but NOT the in-flight vmem
        __builtin_amdgcn_sched_barrier(0);
        asm volatile("s_waitcnt lgkmcnt(0)" ::: "memory");
        __builtin_amdgcn_s_barrier();
        __builtin_amdgcn_sched_barrier(0);

        // MFMA on LDS[buf]
#pragma unroll
        for (int kk = 0; kk < 64; kk += 32) {
            bf16x8 a = *(const bf16x8*)&As[buf][mt * 16 + l15][kk + hi * 8];
            bf16x8 alo = *(const bf16x8*)&Alo[buf][mt * 16 + l15][kk + hi * 8];
            bf16x8 brh = *(const bf16x8*)&Bs[buf][jt * 16 + l15][kk + hi * 8];
            bf16x8 brl = *(const bf16x8*)&Blo[buf][jt * 16 + l15][kk + hi * 8];
            bf16x8 bzh = *(const bf16x8*)&Bs[buf][32 + jt * 16 + l15][kk + hi * 8];
            bf16x8 bzl = *(const bf16x8*)&Blo[buf][32 + jt * 16 + l15][kk + hi * 8];
            bf16x8 bnh = *(const bf16x8*)&Bs[buf][64 + jt * 16 + l15][kk + hi * 8];
            bf16x8 bnl = *(const bf16x8*)&Blo[buf][64 + jt * 16 + l15][kk + hi * 8];
            acc_r = mfma16(a, brh, acc_r);
            acc_r = mfma16(alo, brh, acc_r);
            acc_r = mfma16(a, brl, acc_r);
            acc_z = mfma16(a, bzh, acc_z);
            acc_z = mfma16(alo, bzh, acc_z);
            acc_z = mfma16(a, bzl, acc_z);
            if (k0 < 256) {
                acc_in = mfma16(a, bnh, acc_in);
                acc_in = mfma16(alo, bnh, acc_in);
                acc_in = mfma16(a, bnl, acc_in);
            } else {
                acc_hn = mfma16(a, bnh, acc_hn);
                acc_hn = mfma16(alo, bnh, acc_hn);
                acc_hn = mfma16(a, bnl, acc_hn);
            }
        }

        // rotate prefetched registers
        vaC = vaN; vbC = vbN;
        bhC0 = bhN0; bhC1 = bhN1; bhC2 = bhN2;
        blC0 = blN0; blC1 = blN1; blC2 = blN2;
    }

    int j = jtile * 32 + jt * 16 + l15;
    float bir = bih[j] + bhh[j];
    float biz = bih[512 + j] + bhh[512 + j];
    float bin = bih[1024 + j];
    float bhn = bhh[1024 + j];
#pragma unroll
    for (int r = 0; r < 4; r++) {
        int trw = mtile * 32 + mt * 16 + hi * 4 + r;
        if (trw < TC) {
            float rr = sigm(acc_r[r] + bir);
            float zz = sigm(acc_z[r] + biz);
            float nn = tanhf(acc_in[r] + bin + rr * (acc_hn[r] + bhn));
            float hp = (step > 0) ? outb[((size_t)prevb * TC + trw) * 512 + j] : 0.f;
            outb[((size_t)bsrc * TC + trw) * 512 + j] = (1.f - zz) * nn + zz * hp;
        }
    }
}

// ---------------------------------------------------------------------------
// Persistent decoder chunk (R8, best measured). BOTH decoders per launch,
// 32 WGs: d = blockIdx.x>>4, c = (blockIdx.x>>3)&1 (16-row chain),
// g = blockIdx.x&7 (64-col group; cols j = g*64 + wv*16 + l15).
// Fan-in 8 per (decoder, chain); Wf[3][16] bf16-hi in regs; H fp32; relaxed
// agent atomics. Producer: sc H stores + syncthreads (vmcnt drain) + tid0
// relaxed flag store. Consumer: wave0 lanes 0-7 poll + syncthreads.
// ---------------------------------------------------------------------------
__global__ __launch_bounds__(256, 1) void dec_k(
    const float* __restrict__ giF, const float* __restrict__ giR,
    const float* __restrict__ WhhF, const float* __restrict__ WhhR,
    const float* __restrict__ bhhF, const float* __restrict__ bhhR,
    float* __restrict__ HcurF, float* __restrict__ HcurR,
    const float* __restrict__ HprevF, const float* __restrict__ HprevR,
    int* __restrict__ flags, int t0, int TC) {
    const int d = blockIdx.x >> 4;
    const int c = (blockIdx.x >> 3) & 1;
    const int g = blockIdx.x & 7;
    const float* gi = d ? giR : giF;
    const float* Whh = d ? WhhR : WhhF;
    const float* bhh = d ? bhhR : bhhF;
    float* Hcur = d ? HcurR : HcurF;
    const float* Hprev = d ? HprevR : HprevF;
    int* flg = flags + d * 32 + c * 8;  // 8 flags per (decoder, chain)

    const int tid = threadIdx.x;
    const int lane = tid & 63, wv = tid >> 6;
    const int l15 = lane & 15, hi = lane >> 4;
    const int j_abs = g * 64 + wv * 16 + l15;  // 64 cols per WG, 16 per wave
    const int brow = c * 16;                   // chain's base batch row

    bf16x8 Wf[3][16];
#pragma unroll
    for (int s = 0; s < 3; s++)
#pragma unroll
        for (int kb = 0; kb < 16; kb++)
            Wf[s][kb] = ld8f(Whh + (size_t)(s * 512 + j_abs) * 512 + kb * 32 + hi * 8);

    const float bhr = bhh[j_abs];
    const float bhz = bhh[512 + j_abs];
    const float bhn = bhh[1024 + j_abs];

    float hpreg[4] = {0.f, 0.f, 0.f, 0.f};

    for (int tt = 0; tt < TC; tt++) {
        const int t = t0 + tt;
        float gr[4], gz[4], gn[4];
#pragma unroll
        for (int r = 0; r < 4; r++) {
            int b = brow + hi * 4 + r;
            const float* gp = gi + ((size_t)tt * BATCH + b) * 1536 + j_abs;
            gr[r] = gp[0];
            gz[r] = gp[512];
            gn[r] = gp[1024];
        }

        f32x4 ar = {}, az = {}, an = {};
        float hp[4] = {0.f, 0.f, 0.f, 0.f};
        if (t > 0) {
            const float* base;
            if (tt > 0) {
                // wait until this chain's 8 producer WGs published step t-1
                if (wv == 0 && lane < 8) {
                    while (__hip_atomic_load(&flg[lane], __ATOMIC_RELAXED,
                                             __HIP_MEMORY_SCOPE_AGENT) < t)
                        __builtin_amdgcn_s_sleep(1);
                }
                __syncthreads();
                base = Hcur + (size_t)(tt - 1) * BATCH * 512;
            } else {
                base = Hprev + (size_t)(TC - 1) * BATCH * 512;
            }
            // A fragment: row = brow + l15 (chain's 16 rows), k = kb*32+hi*8
            const float* ap = base + (size_t)(brow + l15) * 512 + hi * 8;
#pragma unroll
            for (int half = 0; half < 2; half++) {
                f32x4 raw[8][2];
#pragma unroll
                for (int q = 0; q < 8; q++) {
                    int kb = half * 8 + q;
                    raw[q][0] = cld_f32x4(ap + kb * 32);
                    raw[q][1] = cld_f32x4(ap + kb * 32 + 4);
                }
#pragma unroll
                for (int q = 0; q < 8; q++) {
                    int kb = half * 8 + q;
                    bf16x8 ah, al;
                    splitv(raw[q][0], raw[q][1], ah, al);
                    ar = mfma16(ah, Wf[0][kb], ar);
                    ar = mfma16(al, Wf[0][kb], ar);
                    az = mfma16(ah, Wf[1][kb], az);
                    az = mfma16(al, Wf[1][kb], az);
                    an = mfma16(ah, Wf[2][kb], an);
                    an = mfma16(al, Wf[2][kb], an);
                }
            }
            if (tt > 0) {
#pragma unroll
                for (int r = 0; r < 4; r++) hp[r] = hpreg[r];
            } else {
#pragma unroll
                for (int r = 0; r < 4; r++) {
                    int b = brow + hi * 4 + r;
                    hp[r] = cld_f32(base + (size_t)b * 512 + j_abs);
                }
            }
        }
#pragma unroll
        for (int r = 0; r < 4; r++) {
            int b = brow + hi * 4 + r;
            float rr = sigm(gr[r] + ar[r] + bhr);
            float zz = sigm(gz[r] + az[r] + bhz);
            float nn = tanhf(gn[r] + rr * (an[r] + bhn));
            float hnew = (1.f - zz) * nn + zz * hp[r];
            cst_f32(&Hcur[((size_t)tt * BATCH + b) * 512 + j_abs], hnew);
            hpreg[r] = hnew;
        }
        // syncthreads emits s_waitcnt vmcnt(0) before s_barrier: all waves'
        // coherent H stores are ACKed at the LLC. tid0 then publishes step t.
        __syncthreads();
        if (tid == 0)
            __hip_atomic_store(&flg[g], t + 1, __ATOMIC_RELAXED,
                               __HIP_MEMORY_SCOPE_AGENT);
    }
}

// ---------------------------------------------------------------------------
// Head: out[b*800 + t0 + tt] = dot(W, H[tt*32+b][:]) + bias  (fp32)
// ---------------------------------------------------------------------------
__global__ __launch_bounds__(256) void post_k(
    const float* __restrict__ H, const float* __restrict__ W,
    const float* __restrict__ bs, float* __restrict__ out, int t0) {
    const int wv = threadIdx.x >> 6, lane = threadIdx.x & 63;
    const int row = blockIdx.x * 4 + wv;
    const int tt = row >> 5, b = row & 31;
    const float bias = bs[0];
    const float* hp = H + (size_t)row * 512 + lane * 8;
    f32x4 h0 = *(const f32x4*)hp;
    f32x4 h1 = *(const f32x4*)(hp + 4);
    f32x4 w0 = *(const f32x4*)(W + lane * 8);
    f32x4 w1 = *(const f32x4*)(W + lane * 8 + 4);
    float s = 0.f;
#pragma unroll
    for (int i = 0; i < 4; i++) s += h0[i] * w0[i] + h1[i] * w1[i];
#pragma unroll
    for (int off = 32; off > 0; off >>= 1) s += __shfl_down(s, off);
    if (lane == 0) out[b * TLEN + t0 + tt] = s + bias;
}

__global__ void zero_k(int* __restrict__ flags) {
    int i = blockIdx.x * 256 + threadIdx.x;
    if (i < 2 * TLEN)
        __hip_atomic_store(&flags[i], 0, __ATOMIC_RELAXED,
                           __HIP_MEMORY_SCOPE_AGENT);
}

// ---------------------------------------------------------------------------
extern "C" void kernel_launch(void* const* d_in, const int* in_sizes, int n_in,
                              void* d_out, int out_size, void* d_ws, size_t ws_size,
                              hipStream_t stream) {
    const int* note = (const int*)d_in[0];
    const float* f0_prev = (const float*)d_in[1];
    const float* rmse_prev = (const float*)d_in[2];
    const float* note_emb = (const float*)d_in[3];
    const float* f0_W = (const float*)d_in[4];
    const float* f0_b = (const float*)d_in[5];
    const float* rmse_W = (const float*)d_in[6];
    const float* rmse_b = (const float*)d_in[7];
    const float* pre1_W = (const float*)d_in[8];
    const float* pre1_b = (const float*)d_in[9];
    const float* pre2_W = (const float*)d_in[10];
    const float* pre2_b = (const float*)d_in[11];
    const float* encf_Wih = (const float*)d_in[12];
    const float* encf_Whh = (const float*)d_in[13];
    const float* encf_bih = (const float*)d_in[14];
    const float* encf_bhh = (const float*)d_in[15];
    const float* encb_Wih = (const float*)d_in[16];
    const float* encb_Whh = (const float*)d_in[17];
    const float* encb_bih = (const float*)d_in[18];
    const float* encb_bhh = (const float*)d_in[19];
    const float* decf_Wih = (const float*)d_in[20];
    const float* decf_Whh = (const float*)d_in[21];
    const float* decf_bih = (const float*)d_in[22];
    const float* decf_bhh = (const float*)d_in[23];
    const float* decr_Wih = (const float*)d_in[24];
    const float* decr_Whh = (const float*)d_in[25];
    const float* decr_bih = (const float*)d_in[26];
    const float* decr_bhh = (const float*)d_in[27];
    const float* postf_W = (const float*)d_in[28];
    const float* postf_b = (const float*)d_in[29];
    const float* postr_W = (const float*)d_in[30];
    const float* postr_b = (const float*)d_in[31];
    float* out = (float*)d_out;  // reference output dtype is float32

    // --- choose chunk size TC from ws_size (multiple of 4, divides 800) ---
    // per-TC bytes: ef/eb 2*65536 + gi 2*196608 + H rings 2*slots*65536,
    // plus constant 9.44 MB pre-split encoder weights.
    const size_t WSPB = (size_t)4 * WELEM * 2;  // 9,437,184 B
    const int tcs[9] = {800, 400, 200, 100, 80, 40, 20, 8, 4};
    int TC = 4;
    for (int i = 0; i < 9; i++) {
        int tc = tcs[i];
        int slots = (tc == TLEN) ? 1 : 2;
        size_t need = (size_t)(2 * 65536 + 2 * 196608 + 2 * slots * 65536) * tc +
                      WSPB + 131072;
        if (ws_size >= need) { TC = tc; break; }
    }
    const int NC = TLEN / TC;
    const int slots = (NC == 1) ? 1 : 2;

    char* ws = (char*)d_ws;
    size_t off = 0;
    auto carve = [&](size_t bytes) {
        void* p = ws + off;
        off += (bytes + 255) & ~(size_t)255;
        return p;
    };
    const size_t slotB = (size_t)65536 * TC;  // TC*32*512*4 bytes (fp32)
    float* ef_c = (float*)carve(slotB);
    float* eb_c = (float*)carve(slotB);
    float* giF_c = (float*)carve((size_t)196608 * TC);
    float* giR_c = (float*)carve((size_t)196608 * TC);
    float* ringF = (float*)carve(slotB * slots);
    float* ringR = (float*)carve(slotB * slots);
    bf16* wsp = (bf16*)carve(WSPB);  // [2 dirs][hi,lo][1536*768] bf16
    int* flags = (int*)carve(2 * TLEN * 4);
    // prenet temporaries alias giF_c (dead once gi is computed): fp32
    float* t1_c = giF_c;                         // 32*TC x 256 fp32
    float* hpre_c = giF_c + (size_t)8192 * TC;   // 32*TC x 256 fp32

    zero_k<<<dim3(7), 256, 0, stream>>>(flags);
    wsplit_k<<<dim3(576, 2), 256, 0, stream>>>(encf_Wih, encf_Whh, encb_Wih,
                                               encb_Whh, wsp);

    const size_t slotE = (size_t)TC * BATCH * 512;

    for (int c = 0; c < NC; c++) {
        const int t0 = c * TC;
        const int mg = TC * 32 / 128;  // 4 | TC -> exact

        gemm01_k<0><<<dim3(mg, 2), 256, 0, stream>>>(note, note_emb, pre1_W, pre1_b,
                                                     t1_c, t0, TC);
        gemm01_k<1><<<dim3(mg, 2), 256, 0, stream>>>(nullptr, t1_c, pre2_W, pre2_b,
                                                     hpre_c, t0, TC);
        const int etiles = (TC + 31) / 32;
        for (int i = 0; i < 32; i++)
            enc_step_k<<<dim3(etiles * 32), 256, 0, stream>>>(
                i, TC, hpre_c, ef_c, eb_c, wsp, encf_bih, encf_bhh, encb_bih,
                encb_bhh);

        // gi for both decoders (gemm2 writes giF after hpre/t1 are dead)
        gemm2_k<<<dim3(mg, 24), 256, 0, stream>>>(ef_c, eb_c, f0_prev, f0_W, f0_b,
                                                  decf_Wih, decf_bih, giF_c, t0, TC);
        gemm2_k<<<dim3(mg, 24), 256, 0, stream>>>(ef_c, eb_c, rmse_prev, rmse_W,
                                                  rmse_b, decr_Wih, decr_bih, giR_c,
                                                  t0, TC);

        float* HcurF = ringF + (size_t)(c & (slots - 1)) * slotE;
        const float* HprevF = ringF + (size_t)((c - 1) & (slots - 1)) * slotE;
        float* HcurR = ringR + (size_t)(c & (slots - 1)) * slotE;
        const float* HprevR = ringR + (size_t)((c - 1) & (slots - 1)) * slotE;

        // BOTH decoders in one launch: 32 WGs, d = bid>>4, chain = (bid>>3)&1
        dec_k<<<dim3(32), 256, 0, stream>>>(giF_c, giR_c, decf_Whh, decr_Whh,
                                            decf_bhh, decr_bhh, HcurF, HcurR,
                                            HprevF, HprevR, flags, t0, TC);

        post_k<<<dim3(TC * 32 / 4), 256, 0, stream>>>(HcurF, postf_W, postf_b,
                                                      out, t0);
        post_k<<<dim3(TC * 32 / 4), 256, 0, stream>>>(HcurR, postr_W, postr_b,
                                                      out + BT, t0);
    }
    (void)in_sizes; (void)n_in; (void)out_size; (void)ws_size;
}